// Round 6
// baseline (1278.347 us; speedup 1.0000x reference)
//
#include <hip/hip_runtime.h>
#include <hip/hip_bf16.h>
#include <math.h>

// dims
#define MMX 64
#define NNX 128
#define DDX 64
#define RDX 128
#define TTX 96
#define LLX 512
#define PROWS 67    // padded rows: m in [-1, 65]
#define PCOLS 130   // padded cols: n in [-1, 128]

typedef short bfx8 __attribute__((ext_vector_type(8)));
typedef float floatx4 __attribute__((ext_vector_type(4)));

__device__ __forceinline__ float gelu(float v) {
  return 0.5f * v * (1.0f + erff(v * 0.70710678118654752f));
}

// ---------------------------------------------------------------------------
// prep: conv weight fp32 [CO][CI][4][3] -> bf16 [dd=dm*3+dn][co][ci]
// ---------------------------------------------------------------------------
__global__ __launch_bounds__(256) void castw_kernel(
    const float* __restrict__ w, __hip_bfloat16* __restrict__ o, int CO, int CI) {
  int i = blockIdx.x * 256 + threadIdx.x;      // CO*CI*12 total
  int ci = i % CI;
  int t = i / CI;
  int co = t % CO;
  int dd = t / CO;
  o[i] = __float2bfloat16(w[(size_t)(co * CI + ci) * 12 + dd]);
}

// ---------------------------------------------------------------------------
// prep: head weight fp32 [96][f=d*128+n] -> bf16 [96][fh=n*64+d]
// ---------------------------------------------------------------------------
__global__ __launch_bounds__(256) void headw_kernel(
    const float* __restrict__ hw, __hip_bfloat16* __restrict__ o) {
  int i = blockIdx.x * 256 + threadIdx.x;      // 96*8192 total
  int fh = i & 8191;
  int t = i >> 13;
  int d = fh & 63;
  int n = fh >> 6;
  o[i] = __float2bfloat16(hw[(size_t)t * 8192 + d * 128 + n]);
}

// ---------------------------------------------------------------------------
// embed: x [B*M, L] fp32 -> X [Bc*M, N, D] fp32 (k=8 stride=4, edge-pad right)
// ---------------------------------------------------------------------------
__global__ __launch_bounds__(256) void embed_kernel(
    const float* __restrict__ x, const float* __restrict__ w,
    const float* __restrict__ bias, float* __restrict__ xe, int bm_off) {
  int tid = blockIdx.x * 256 + threadIdx.x;
  int d  = tid & 63;
  int n  = (tid >> 6) & 127;
  int bm = tid >> 13;
  const float* xr = x + (size_t)(bm_off + bm) * LLX;
  float acc = bias[d];
  int base = n * 4;
#pragma unroll
  for (int p = 0; p < 8; ++p) {
    int i = base + p;
    if (i > LLX - 1) i = LLX - 1;
    acc += w[d * 8 + p] * xr[i];
  }
  xe[tid] = acc;
}

// ---------------------------------------------------------------------------
// depthwise conv over M (k=4, zero-pad 1/2): X fp32 [b,m,n,d] -> Yp bf16 padded
// Rolling register window over m: X read ONCE.
// Yp layout [b][PROWS][PCOLS][64], interior at [m+1][n+1]; halos pre-zeroed.
// ---------------------------------------------------------------------------
__global__ __launch_bounds__(256) void dw_kernel(
    const float* __restrict__ xe, const float* __restrict__ w,
    const float* __restrict__ bias, __hip_bfloat16* __restrict__ yp) {
  const int tid = threadIdx.x;
  const int d = tid & 63;
  const int n = ((blockIdx.x & 31) << 2) + (tid >> 6);
  const int b = blockIdx.x >> 5;
  const int c = n * DDX + d;
  const float w0 = w[c * 4 + 0], w1 = w[c * 4 + 1];
  const float w2 = w[c * 4 + 2], w3 = w[c * 4 + 3];
  const float bv = bias[c];
  const float* src = xe + ((size_t)b * MMX * NNX + n) * DDX + d;
  __hip_bfloat16* dst = yp + (((size_t)b * PROWS + 1) * PCOLS + n + 1) * DDX + d;
  const int sstr = NNX * DDX;
  const int dstr = PCOLS * DDX;
  // taps: out[m] = w0*x[m-1] + w1*x[m] + w2*x[m+1] + w3*x[m+2], zero-pad
  float xm1 = 0.f, x0 = src[0], xp1 = src[sstr], xp2;
#pragma unroll 4
  for (int m = 0; m < MMX; ++m) {
    xp2 = (m + 2 < MMX) ? src[(size_t)(m + 2) * sstr] : 0.f;
    float acc = bv + w0 * xm1 + w1 * x0 + w2 * xp1 + w3 * xp2;
    dst[(size_t)m * dstr] = __float2bfloat16(acc);
    xm1 = x0; x0 = xp1; xp1 = xp2;
  }
}

// ---------------------------------------------------------------------------
// MFMA conv2d 4x3. Block = one (b,m). WPX waves along px x (4/WPX) along co.
// r5 decomposition: WPX=4, WCO=1 for BOTH convs -- each wave owns 32 px and
// ALL co. This maximizes CT (A-reuse per LDS read). Aggregate LDS port
// cycles per block: 768/CT x 12cyc vs 7450cyc of MFMA -> CT=8/4 is
// MFMA-bound (CT=2 was LDS-bound at 9216 cyc).
// SPILL FIX (r4, kept): epilogue fully unrolled, all acc indices
// compile-time (prior runtime-h indexing demoted acc to scratch:
// VGPR=84, 830MB/dispatch scratch writes, MfmaUtil 8.8%).
// Bf loaded per-(dn,kc) to cap live range (CT bfx8 at a time).
// T14 async-STAGE: dm+1 prefetch issued AFTER the post-staging barrier so it
// flies under this dm's MFMA phase (barriers drain vmcnt).
// XCD-swizzled (b,m). in padded [b][67][130][CIN]; wT [12][COUT][CIN].
// GELU: write Hp padded interior (bf16). else: X += resid (fp32) and Xb bf16.
// ---------------------------------------------------------------------------
template <int CIN, int COUT, bool GELU, int WPX>
__global__ __launch_bounds__(256) void conv_lds(
    const __hip_bfloat16* __restrict__ in,
    const __hip_bfloat16* __restrict__ wT,
    const float* __restrict__ bias,
    __hip_bfloat16* __restrict__ hout,   // padded [b][67][130][COUT]
    float* xio,                          // [b][64][128][COUT] fp32
    __hip_bfloat16* __restrict__ xb) {   // [b][64][128][COUT] bf16
  constexpr int ASTR = CIN + 8;          // LDS row stride (balanced 16B slots)
  constexpr int KC = CIN / 32;           // k-chunks per (dm,dn)
  constexpr int WCO = 4 / WPX;           // waves along co
  constexpr int PT = 8 / WPX;            // 16-px tiles per wave
  constexpr int CT = COUT / 16 / WCO;    // 16-co tiles per wave
  constexpr int TOTCH = 130 * CIN / 8;   // uint4 chunks per padded row
  constexpr int PER = (TOTCH + 255) / 256;  // 5 (conv1) / 9 (conv2)
  __shared__ short smem[130 * ASTR];     // conv1 18.7 KB, conv2 35.4 KB

  // bijective XCD swizzle (grid = Bc*64, always %8==0)
  const int nwg = gridDim.x;
  const int wid = (blockIdx.x & 7) * (nwg >> 3) + (blockIdx.x >> 3);
  const int m = wid & 63;
  const int b = wid >> 6;
  const int tid = threadIdx.x;
  const int lane = tid & 63;
  const int w = tid >> 6;
  const int wco = w % WCO;
  const int wpx = w / WCO;
  const int wc0 = wco * (16 * CT);
  const int px0 = wpx * (16 * PT);
  const int l15 = lane & 15;
  const int quad = lane >> 4;

  floatx4 acc[PT][CT];
#pragma unroll
  for (int i = 0; i < PT; ++i)
#pragma unroll
    for (int j = 0; j < CT; ++j) acc[i][j] = (floatx4)0.f;

  const __hip_bfloat16* inrow = in + ((size_t)b * PROWS + m) * PCOLS * CIN;

  // prologue: issue dm=0 row loads into registers
  uint4 st[PER];
  {
    const uint4* src = (const uint4*)inrow;
#pragma unroll
    for (int p = 0; p < PER; ++p) {
      int idx = tid + p * 256;
      if (idx < TOTCH) st[p] = src[idx];
    }
  }

#pragma unroll 1
  for (int dm = 0; dm < 4; ++dm) {
    __syncthreads();  // (A) prior K-step smem reads done; drains prefetch
    // write already-landed staged regs -> LDS (pure lgkm)
#pragma unroll
    for (int p = 0; p < PER; ++p) {
      int idx = tid + p * 256;
      if (idx < TOTCH) {
        int col = idx / (CIN / 8), cg = idx % (CIN / 8);
        *(uint4*)&smem[col * ASTR + cg * 8] = st[p];
      }
    }
    __syncthreads();  // (B) staging visible

    // issue NEXT row's loads AFTER the barrier -> fly under this dm's MFMAs
    if (dm < 3) {
      const uint4* src = (const uint4*)(inrow + (size_t)(dm + 1) * PCOLS * CIN);
#pragma unroll
      for (int p = 0; p < PER; ++p) {
        int idx = tid + p * 256;
        if (idx < TOTCH) st[p] = src[idx];
      }
    }

    const __hip_bfloat16* wbase = wT + (size_t)dm * 3 * COUT * CIN;
#pragma unroll
    for (int dn = 0; dn < 3; ++dn) {
#pragma unroll
      for (int kc = 0; kc < KC; ++kc) {
        const int kb = kc * 32 + quad * 8;
        // B fragments for THIS (dn,kc) only (live range: CT bfx8)
        bfx8 Bf[CT];
#pragma unroll
        for (int j = 0; j < CT; ++j)
          Bf[j] = *(const bfx8*)(
              wbase + ((size_t)dn * COUT + wc0 + 16 * j + l15) * CIN +
              kc * 32 + quad * 8);
        bfx8 a[PT];
#pragma unroll
        for (int i = 0; i < PT; ++i)
          a[i] = *(const bfx8*)&smem[(px0 + 16 * i + l15 + dn) * ASTR + kb];
#pragma unroll
        for (int j = 0; j < CT; ++j)
#pragma unroll
          for (int i = 0; i < PT; ++i)
            acc[i][j] = __builtin_amdgcn_mfma_f32_16x16x32_bf16(
                a[i], Bf[j], acc[i][j], 0, 0, 0);
      }
    }
  }

  // bias
  float bs[CT];
#pragma unroll
  for (int j = 0; j < CT; ++j) bs[j] = bias[wc0 + 16 * j + l15];

  // epilogue: LDS transpose per 64-px half -> coalesced wide stores.
  // FULLY UNROLLED over h (compile-time acc indices -- no scratch demotion).
  // Unified tile mapping: wave owns global 16-px tiles g = wpx*PT + i;
  // tile g belongs to half h iff g>>2 == h; row-in-half ii = g&3.
  __syncthreads();  // all K-loop smem reads done before reuse
#pragma unroll
  for (int h = 0; h < 2; ++h) {
    if (GELU) {
      constexpr int STR2 = COUT + 8;     // shorts
      short* t2 = smem;
#pragma unroll
      for (int i = 0; i < PT; ++i) {
        int g = wpx * PT + i;
        if ((g >> 2) == h) {
          int ii = g & 3;
#pragma unroll
          for (int j = 0; j < CT; ++j)
#pragma unroll
            for (int r = 0; r < 4; ++r) {
              int pl = 16 * ii + quad * 4 + r;
              __hip_bfloat16 bv = __float2bfloat16(gelu(acc[i][j][r] + bs[j]));
              t2[pl * STR2 + wc0 + 16 * j + l15] = *(short*)&bv;
            }
        }
      }
      __syncthreads();
      constexpr int CHUNKS = 64 * COUT / 8;   // 1024
      size_t gbase = (((size_t)b * PROWS + m + 1) * PCOLS + 1 + h * 64) * COUT;
      for (int idx = tid; idx < CHUNKS; idx += 256) {
        int px = idx / (COUT / 8), cg = idx % (COUT / 8);
        uint4 v = *(uint4*)&t2[px * STR2 + cg * 8];
        *(uint4*)(hout + gbase + (size_t)px * COUT + cg * 8) = v;
      }
      __syncthreads();
    } else {
      constexpr int STRF = COUT + 4;     // floats
      float* tf = (float*)smem;
#pragma unroll
      for (int i = 0; i < PT; ++i) {
        int g = wpx * PT + i;
        if ((g >> 2) == h) {
          int ii = g & 3;
#pragma unroll
          for (int j = 0; j < CT; ++j)
#pragma unroll
            for (int r = 0; r < 4; ++r) {
              int pl = 16 * ii + quad * 4 + r;
              tf[pl * STRF + wc0 + 16 * j + l15] = acc[i][j][r] + bs[j];
            }
        }
      }
      __syncthreads();
      constexpr int CHUNKS = 64 * COUT / 4;   // 1024
      size_t gbase = (((size_t)b * MMX + m) * NNX + h * 64) * COUT;
      for (int idx = tid; idx < CHUNKS; idx += 256) {
        int px = idx / (COUT / 4), cg = idx % (COUT / 4);
        float4 a4 = *(float4*)&tf[px * STRF + cg * 4];
        size_t gx = gbase + (size_t)px * COUT + cg * 4;
        float4 xv = *(float4*)(xio + gx);
        float4 rr = make_float4(a4.x + xv.x, a4.y + xv.y, a4.z + xv.z, a4.w + xv.w);
        *(float4*)(xio + gx) = rr;
        __hip_bfloat16 o0 = __float2bfloat16(rr.x), o1 = __float2bfloat16(rr.y);
        __hip_bfloat16 o2 = __float2bfloat16(rr.z), o3 = __float2bfloat16(rr.w);
        ushort4 ov = make_ushort4(*(unsigned short*)&o0, *(unsigned short*)&o1,
                                  *(unsigned short*)&o2, *(unsigned short*)&o3);
        *(ushort4*)(xb + gx) = ov;
      }
      __syncthreads();
    }
  }
}

// ---------------------------------------------------------------------------
// head split-K: P[ks][bm][t] = sum_{k in slice} Xb[bm][k] * hwT[t][k]
// grid = Bc * 8; block = 64 bm x 96 t x K=1024. 4 waves = 16 bm each.
// ---------------------------------------------------------------------------
__global__ __launch_bounds__(256) void head_split(
    const __hip_bfloat16* __restrict__ xb,   // [nbm][8192]
    const __hip_bfloat16* __restrict__ hwT,  // [96][8192]
    float* __restrict__ P, int nbm) {        // [8][nbm][96]
  const int ks = blockIdx.x & 7;
  const int bm0 = (blockIdx.x >> 3) * 64;
  const int lane = threadIdx.x & 63;
  const int w = threadIdx.x >> 6;
  const int l15 = lane & 15;
  const int quad = lane >> 4;
  const int bmw = bm0 + w * 16;

  floatx4 acc[6];
#pragma unroll
  for (int j = 0; j < 6; ++j) acc[j] = (floatx4)0.f;

  const int k0 = ks * 1024;
  const __hip_bfloat16* abase = xb + (size_t)(bmw + l15) * 8192 + k0;
  const __hip_bfloat16* bbase = hwT + (size_t)l15 * 8192 + k0;
#pragma unroll 4
  for (int kc = 0; kc < 32; ++kc) {
    const int kb = kc * 32 + quad * 8;
    bfx8 a = *(const bfx8*)(abase + kb);
#pragma unroll
    for (int j = 0; j < 6; ++j) {
      bfx8 bv = *(const bfx8*)(bbase + (size_t)(16 * j) * 8192 + kb);
      acc[j] = __builtin_amdgcn_mfma_f32_16x16x32_bf16(a, bv, acc[j], 0, 0, 0);
    }
  }
#pragma unroll
  for (int j = 0; j < 6; ++j) {
    int t = 16 * j + l15;
#pragma unroll
    for (int r = 0; r < 4; ++r) {
      int bm = bmw + quad * 4 + r;
      P[((size_t)ks * nbm + bm) * TTX + t] = acc[j][r];
    }
  }
}

__global__ __launch_bounds__(256) void head_reduce(
    const float* __restrict__ P, const float* __restrict__ hb,
    float* __restrict__ out, int nbm, int bm_off) {
  int i = blockIdx.x * 256 + threadIdx.x;    // nbm*96
  int t = i % TTX;
  int bm = i / TTX;
  float s = hb[t];
#pragma unroll
  for (int ks = 0; ks < 8; ++ks) s += P[((size_t)ks * nbm + bm) * TTX + t];
  out[(size_t)(bm_off + bm) * TTX + t] = s;
}

// ---------------------------------------------------------------------------
extern "C" void kernel_launch(void* const* d_in, const int* in_sizes, int n_in,
                              void* d_out, int out_size, void* d_ws, size_t ws_size,
                              hipStream_t stream) {
  const float* x      = (const float*)d_in[0];
  const float* emb_w  = (const float*)d_in[1];
  const float* emb_b  = (const float*)d_in[2];
  const float* head_w = (const float*)d_in[3];
  const float* head_b = (const float*)d_in[4];
  const float* dw_w1  = (const float*)d_in[5];
  const float* dw_b1  = (const float*)d_in[6];
  const float* f11_w  = (const float*)d_in[7];
  const float* f11_b  = (const float*)d_in[8];
  const float* f12_w  = (const float*)d_in[9];
  const float* f12_b  = (const float*)d_in[10];
  const float* dw_w2  = (const float*)d_in[11];
  const float* dw_b2  = (const float*)d_in[12];
  const float* f21_w  = (const float*)d_in[13];
  const float* f21_b  = (const float*)d_in[14];
  const float* f22_w  = (const float*)d_in[15];
  const float* f22_b  = (const float*)d_in[16];

  // fixed: 4 conv wT (98304 bf16 each) + hwT (786432 bf16)
  const size_t WEL = 98304, HWEL = 786432;
  __hip_bfloat16* wt11 = (__hip_bfloat16*)d_ws;
  __hip_bfloat16* wt12 = wt11 + WEL;
  __hip_bfloat16* wt21 = wt12 + WEL;
  __hip_bfloat16* wt22 = wt21 + WEL;
  __hip_bfloat16* hwT  = wt22 + WEL;
  char* dyn = (char*)(hwT + HWEL);
  const size_t fixed_bytes = (4 * WEL + HWEL) * 2;

  const size_t YP_B = (size_t)PROWS * PCOLS * DDX * 2;    // 1,114,880
  const size_t HP_B = (size_t)PROWS * PCOLS * RDX * 2;    // 2,229,760
  const size_t X_B  = (size_t)MMX * NNX * DDX * 4;        // 2,097,152
  const size_t XB_B = (size_t)MMX * NNX * DDX * 2;        // 1,048,576
  const size_t P_B  = (size_t)8 * MMX * TTX * 4;          //   196,608
  const size_t PER_B = YP_B + HP_B + X_B + XB_B + P_B;
  int Bc = 32;
  while (Bc > 1 && fixed_bytes + (size_t)Bc * PER_B > ws_size) Bc >>= 1;

  __hip_bfloat16* Yp = (__hip_bfloat16*)dyn;
  __hip_bfloat16* Hp = (__hip_bfloat16*)(dyn + (size_t)Bc * YP_B);
  float* X  = (float*)(dyn + (size_t)Bc * (YP_B + HP_B));
  __hip_bfloat16* Xb = (__hip_bfloat16*)(dyn + (size_t)Bc * (YP_B + HP_B + X_B));
  float* P  = (float*)(dyn + (size_t)Bc * (YP_B + HP_B + X_B + XB_B));
  const int nbm = Bc * MMX;

  // prep (once per launch)
  castw_kernel<<<384, 256, 0, stream>>>(f11_w, wt11, RDX, DDX);
  castw_kernel<<<384, 256, 0, stream>>>(f12_w, wt12, DDX, RDX);
  castw_kernel<<<384, 256, 0, stream>>>(f21_w, wt21, RDX, DDX);
  castw_kernel<<<384, 256, 0, stream>>>(f22_w, wt22, DDX, RDX);
  headw_kernel<<<3072, 256, 0, stream>>>(head_w, hwT);
  // zero padded halo buffers (ws is re-poisoned before every timed launch)
  hipMemsetAsync(Yp, 0, (size_t)Bc * (YP_B + HP_B), stream);

  for (int b0 = 0; b0 < 32; b0 += Bc) {
    int bm_off = b0 * MMX;
    embed_kernel<<<Bc * 2048, 256, 0, stream>>>(x, emb_w, emb_b, X, bm_off);

    for (int l = 0; l < 2; ++l) {
      const float* dwW = l ? dw_w2 : dw_w1;
      const float* dwB = l ? dw_b2 : dw_b1;
      const __hip_bfloat16* w1 = l ? wt21 : wt11;
      const float* b1 = l ? f21_b : f11_b;
      const __hip_bfloat16* w2 = l ? wt22 : wt12;
      const float* b2 = l ? f22_b : f12_b;

      dw_kernel<<<Bc * 32, 256, 0, stream>>>(X, dwW, dwB, Yp);
      conv_lds<DDX, RDX, true, 4>
          <<<Bc * MMX, 256, 0, stream>>>(Yp, w1, b1, Hp, nullptr, nullptr);
      conv_lds<RDX, DDX, false, 4>
          <<<Bc * MMX, 256, 0, stream>>>(Hp, w2, b2, nullptr, X, Xb);
    }

    head_split<<<Bc * 8, 256, 0, stream>>>(Xb, hwT, P, nbm);
    head_reduce<<<Bc * 24, 256, 0, stream>>>(P, head_b, (float*)d_out, nbm, bm_off);
  }
}

// Round 10
// 839.227 us; speedup vs baseline: 1.5232x; 1.5232x over previous
//
#include <hip/hip_runtime.h>
#include <hip/hip_bf16.h>
#include <math.h>

// dims
#define MMX 64
#define NNX 128
#define DDX 64
#define RDX 128
#define TTX 96
#define LLX 512
#define PROWS 67    // padded rows: m in [-1, 65]
#define PCOLS 130   // padded cols: n in [-1, 128]

typedef short bfx8 __attribute__((ext_vector_type(8)));
typedef float floatx4 __attribute__((ext_vector_type(4)));

__device__ __forceinline__ float gelu(float v) {
  return 0.5f * v * (1.0f + erff(v * 0.70710678118654752f));
}

// ---------------------------------------------------------------------------
// prep: conv weight fp32 [CO][CI][4][3] -> bf16 [dd=dm*3+dn][co][ci]
// ---------------------------------------------------------------------------
__global__ __launch_bounds__(256) void castw_kernel(
    const float* __restrict__ w, __hip_bfloat16* __restrict__ o, int CO, int CI) {
  int i = blockIdx.x * 256 + threadIdx.x;      // CO*CI*12 total
  int ci = i % CI;
  int t = i / CI;
  int co = t % CO;
  int dd = t / CO;
  o[i] = __float2bfloat16(w[(size_t)(co * CI + ci) * 12 + dd]);
}

// ---------------------------------------------------------------------------
// prep: head weight fp32 [96][f=d*128+n] -> bf16 [96][fh=n*64+d]
// ---------------------------------------------------------------------------
__global__ __launch_bounds__(256) void headw_kernel(
    const float* __restrict__ hw, __hip_bfloat16* __restrict__ o) {
  int i = blockIdx.x * 256 + threadIdx.x;      // 96*8192 total
  int fh = i & 8191;
  int t = i >> 13;
  int d = fh & 63;
  int n = fh >> 6;
  o[i] = __float2bfloat16(hw[(size_t)t * 8192 + d * 128 + n]);
}

// ---------------------------------------------------------------------------
// embed: x [B*M, L] fp32 -> X [Bc*M, N, D] fp32 (k=8 stride=4, edge-pad right)
// ---------------------------------------------------------------------------
__global__ __launch_bounds__(256) void embed_kernel(
    const float* __restrict__ x, const float* __restrict__ w,
    const float* __restrict__ bias, float* __restrict__ xe, int bm_off) {
  int tid = blockIdx.x * 256 + threadIdx.x;
  int d  = tid & 63;
  int n  = (tid >> 6) & 127;
  int bm = tid >> 13;
  const float* xr = x + (size_t)(bm_off + bm) * LLX;
  float acc = bias[d];
  int base = n * 4;
#pragma unroll
  for (int p = 0; p < 8; ++p) {
    int i = base + p;
    if (i > LLX - 1) i = LLX - 1;
    acc += w[d * 8 + p] * xr[i];
  }
  xe[tid] = acc;
}

// ---------------------------------------------------------------------------
// depthwise conv over M (k=4, zero-pad 1/2): X fp32 [b,m,n,d] -> Yp bf16 padded
// Rolling register window over m: X read ONCE.
// Yp layout [b][PROWS][PCOLS][64], interior at [m+1][n+1]; halos pre-zeroed.
// ---------------------------------------------------------------------------
__global__ __launch_bounds__(256) void dw_kernel(
    const float* __restrict__ xe, const float* __restrict__ w,
    const float* __restrict__ bias, __hip_bfloat16* __restrict__ yp) {
  const int tid = threadIdx.x;
  const int d = tid & 63;
  const int n = ((blockIdx.x & 31) << 2) + (tid >> 6);
  const int b = blockIdx.x >> 5;
  const int c = n * DDX + d;
  const float w0 = w[c * 4 + 0], w1 = w[c * 4 + 1];
  const float w2 = w[c * 4 + 2], w3 = w[c * 4 + 3];
  const float bv = bias[c];
  const float* src = xe + ((size_t)b * MMX * NNX + n) * DDX + d;
  __hip_bfloat16* dst = yp + (((size_t)b * PROWS + 1) * PCOLS + n + 1) * DDX + d;
  const int sstr = NNX * DDX;
  const int dstr = PCOLS * DDX;
  // taps: out[m] = w0*x[m-1] + w1*x[m] + w2*x[m+1] + w3*x[m+2], zero-pad
  float xm1 = 0.f, x0 = src[0], xp1 = src[sstr], xp2;
#pragma unroll 4
  for (int m = 0; m < MMX; ++m) {
    xp2 = (m + 2 < MMX) ? src[(size_t)(m + 2) * sstr] : 0.f;
    float acc = bv + w0 * xm1 + w1 * x0 + w2 * xp1 + w3 * xp2;
    dst[(size_t)m * dstr] = __float2bfloat16(acc);
    xm1 = x0; x0 = xp1; xp1 = xp2;
  }
}

// ---------------------------------------------------------------------------
// MFMA conv2d 4x3. Block = one (b,m). WPX waves along px x (4/WPX) along co.
// r7: REVERT r5's WPX=4/WCO=1 (it made every wave load ALL COUT weight
// fragments -- 4x per-wave L2 loads, 8-load->waitcnt->8-MFMA phases, 300cyc
// stall per 40cyc work, MfmaUtil 7%). Back to the benched co-split:
//   conv1 (64->128): WPX=1 -> wave = 128px x 32co (CT=2, 2 Bf loads/phase)
//   conv2 (128->64): WPX=2 -> wave =  64px x 32co (CT=2)
// KEPT from r4/r6: fully-unrolled epilogue (compile-time acc indices; the
// runtime-h indexing demoted acc to scratch: VGPR=84, 830MB scratch writes).
// KEPT: Bf loaded per-(dn,kc) (8 VGPR live), and a read per-px-tile
// inside the MFMA loop (4 VGPR live, was a[PT]=32) -> conv1 demand ~111 VGPR,
// conv2 ~95 -> 4 waves/SIMD, no spill.
// T14 async-STAGE: dm+1 prefetch issued AFTER the post-staging barrier so it
// flies under this dm's MFMA phase (barriers drain vmcnt).
// XCD-swizzled (b,m). in padded [b][67][130][CIN]; wT [12][COUT][CIN].
// GELU: write Hp padded interior (bf16). else: X += resid (fp32) and Xb bf16.
// NEXT-BENCH CHECK: conv1 WRITE_SIZE should drop 130MB -> ~70MB if the
// residual-spill theory is right; if it stays ~2x Hp, the model is wrong.
// ---------------------------------------------------------------------------
template <int CIN, int COUT, bool GELU, int WPX>
__global__ __launch_bounds__(256) void conv_lds(
    const __hip_bfloat16* __restrict__ in,
    const __hip_bfloat16* __restrict__ wT,
    const float* __restrict__ bias,
    __hip_bfloat16* __restrict__ hout,   // padded [b][67][130][COUT]
    float* xio,                          // [b][64][128][COUT] fp32
    __hip_bfloat16* __restrict__ xb) {   // [b][64][128][COUT] bf16
  constexpr int ASTR = CIN + 8;          // LDS row stride (2-way bank alias max)
  constexpr int KC = CIN / 32;           // k-chunks per (dm,dn)
  constexpr int WCO = 4 / WPX;           // waves along co
  constexpr int PT = 8 / WPX;            // 16-px tiles per wave
  constexpr int CT = COUT / 16 / WCO;    // 16-co tiles per wave (=2 both convs)
  constexpr int TOTCH = 130 * CIN / 8;   // uint4 chunks per padded row
  constexpr int PER = (TOTCH + 255) / 256;  // 5 (conv1) / 9 (conv2)
  __shared__ short smem[130 * ASTR];     // conv1 18.7 KB, conv2 35.4 KB

  // bijective XCD swizzle (grid = Bc*64, always %8==0)
  const int nwg = gridDim.x;
  const int wid = (blockIdx.x & 7) * (nwg >> 3) + (blockIdx.x >> 3);
  const int m = wid & 63;
  const int b = wid >> 6;
  const int tid = threadIdx.x;
  const int lane = tid & 63;
  const int w = tid >> 6;
  const int wco = w % WCO;
  const int wpx = w / WCO;
  const int wc0 = wco * (16 * CT);
  const int px0 = wpx * (16 * PT);
  const int l15 = lane & 15;
  const int quad = lane >> 4;

  floatx4 acc[PT][CT];
#pragma unroll
  for (int i = 0; i < PT; ++i)
#pragma unroll
    for (int j = 0; j < CT; ++j) acc[i][j] = (floatx4)0.f;

  const __hip_bfloat16* inrow = in + ((size_t)b * PROWS + m) * PCOLS * CIN;

  // prologue: issue dm=0 row loads into registers
  uint4 st[PER];
  {
    const uint4* src = (const uint4*)inrow;
#pragma unroll
    for (int p = 0; p < PER; ++p) {
      int idx = tid + p * 256;
      if (idx < TOTCH) st[p] = src[idx];
    }
  }

#pragma unroll 1
  for (int dm = 0; dm < 4; ++dm) {
    __syncthreads();  // (A) prior K-step smem reads done; drains prefetch
    // write already-landed staged regs -> LDS (pure lgkm)
#pragma unroll
    for (int p = 0; p < PER; ++p) {
      int idx = tid + p * 256;
      if (idx < TOTCH) {
        int col = idx / (CIN / 8), cg = idx % (CIN / 8);
        *(uint4*)&smem[col * ASTR + cg * 8] = st[p];
      }
    }
    __syncthreads();  // (B) staging visible

    // issue NEXT row's loads AFTER the barrier -> fly under this dm's MFMAs
    if (dm < 3) {
      const uint4* src = (const uint4*)(inrow + (size_t)(dm + 1) * PCOLS * CIN);
#pragma unroll
      for (int p = 0; p < PER; ++p) {
        int idx = tid + p * 256;
        if (idx < TOTCH) st[p] = src[idx];
      }
    }

    const __hip_bfloat16* wbase = wT + (size_t)dm * 3 * COUT * CIN;
#pragma unroll
    for (int dn = 0; dn < 3; ++dn) {
#pragma unroll
      for (int kc = 0; kc < KC; ++kc) {
        const int kb = kc * 32 + quad * 8;
        // B fragments for THIS (dn,kc) only (live range: CT=2 bfx8)
        bfx8 Bf[CT];
#pragma unroll
        for (int j = 0; j < CT; ++j)
          Bf[j] = *(const bfx8*)(
              wbase + ((size_t)dn * COUT + wc0 + 16 * j + l15) * CIN +
              kc * 32 + quad * 8);
#pragma unroll
        for (int i = 0; i < PT; ++i) {
          // A fragment per px-tile (live range: 1 bfx8; scheduler pipelines)
          bfx8 a = *(const bfx8*)&smem[(px0 + 16 * i + l15 + dn) * ASTR + kb];
#pragma unroll
          for (int j = 0; j < CT; ++j)
            acc[i][j] = __builtin_amdgcn_mfma_f32_16x16x32_bf16(
                a, Bf[j], acc[i][j], 0, 0, 0);
        }
      }
    }
  }

  // bias
  float bs[CT];
#pragma unroll
  for (int j = 0; j < CT; ++j) bs[j] = bias[wc0 + 16 * j + l15];

  // epilogue: LDS transpose per 64-px half -> coalesced wide stores.
  // FULLY UNROLLED over h (compile-time acc indices -- no scratch demotion).
  // Unified tile mapping: wave owns global 16-px tiles g = wpx*PT + i;
  // tile g belongs to half h iff g>>2 == h; row-in-half ii = g&3.
  __syncthreads();  // all K-loop smem reads done before reuse
#pragma unroll
  for (int h = 0; h < 2; ++h) {
    if (GELU) {
      constexpr int STR2 = COUT + 8;     // shorts
      short* t2 = smem;
#pragma unroll
      for (int i = 0; i < PT; ++i) {
        int g = wpx * PT + i;
        if ((g >> 2) == h) {
          int ii = g & 3;
#pragma unroll
          for (int j = 0; j < CT; ++j)
#pragma unroll
            for (int r = 0; r < 4; ++r) {
              int pl = 16 * ii + quad * 4 + r;
              __hip_bfloat16 bv = __float2bfloat16(gelu(acc[i][j][r] + bs[j]));
              t2[pl * STR2 + wc0 + 16 * j + l15] = *(short*)&bv;
            }
        }
      }
      __syncthreads();
      constexpr int CHUNKS = 64 * COUT / 8;   // 1024
      size_t gbase = (((size_t)b * PROWS + m + 1) * PCOLS + 1 + h * 64) * COUT;
      for (int idx = tid; idx < CHUNKS; idx += 256) {
        int px = idx / (COUT / 8), cg = idx % (COUT / 8);
        uint4 v = *(uint4*)&t2[px * STR2 + cg * 8];
        *(uint4*)(hout + gbase + (size_t)px * COUT + cg * 8) = v;
      }
      __syncthreads();
    } else {
      constexpr int STRF = COUT + 4;     // floats
      float* tf = (float*)smem;
#pragma unroll
      for (int i = 0; i < PT; ++i) {
        int g = wpx * PT + i;
        if ((g >> 2) == h) {
          int ii = g & 3;
#pragma unroll
          for (int j = 0; j < CT; ++j)
#pragma unroll
            for (int r = 0; r < 4; ++r) {
              int pl = 16 * ii + quad * 4 + r;
              tf[pl * STRF + wc0 + 16 * j + l15] = acc[i][j][r] + bs[j];
            }
        }
      }
      __syncthreads();
      constexpr int CHUNKS = 64 * COUT / 4;   // 1024
      size_t gbase = (((size_t)b * MMX + m) * NNX + h * 64) * COUT;
      for (int idx = tid; idx < CHUNKS; idx += 256) {
        int px = idx / (COUT / 4), cg = idx % (COUT / 4);
        float4 a4 = *(float4*)&tf[px * STRF + cg * 4];
        size_t gx = gbase + (size_t)px * COUT + cg * 4;
        float4 xv = *(float4*)(xio + gx);
        float4 rr = make_float4(a4.x + xv.x, a4.y + xv.y, a4.z + xv.z, a4.w + xv.w);
        *(float4*)(xio + gx) = rr;
        __hip_bfloat16 o0 = __float2bfloat16(rr.x), o1 = __float2bfloat16(rr.y);
        __hip_bfloat16 o2 = __float2bfloat16(rr.z), o3 = __float2bfloat16(rr.w);
        ushort4 ov = make_ushort4(*(unsigned short*)&o0, *(unsigned short*)&o1,
                                  *(unsigned short*)&o2, *(unsigned short*)&o3);
        *(ushort4*)(xb + gx) = ov;
      }
      __syncthreads();
    }
  }
}

// ---------------------------------------------------------------------------
// head split-K: P[ks][bm][t] = sum_{k in slice} Xb[bm][k] * hwT[t][k]
// grid = Bc * 8; block = 64 bm x 96 t x K=1024. 4 waves = 16 bm each.
// ---------------------------------------------------------------------------
__global__ __launch_bounds__(256) void head_split(
    const __hip_bfloat16* __restrict__ xb,   // [nbm][8192]
    const __hip_bfloat16* __restrict__ hwT,  // [96][8192]
    float* __restrict__ P, int nbm) {        // [8][nbm][96]
  const int ks = blockIdx.x & 7;
  const int bm0 = (blockIdx.x >> 3) * 64;
  const int lane = threadIdx.x & 63;
  const int w = threadIdx.x >> 6;
  const int l15 = lane & 15;
  const int quad = lane >> 4;
  const int bmw = bm0 + w * 16;

  floatx4 acc[6];
#pragma unroll
  for (int j = 0; j < 6; ++j) acc[j] = (floatx4)0.f;

  const int k0 = ks * 1024;
  const __hip_bfloat16* abase = xb + (size_t)(bmw + l15) * 8192 + k0;
  const __hip_bfloat16* bbase = hwT + (size_t)l15 * 8192 + k0;
#pragma unroll 4
  for (int kc = 0; kc < 32; ++kc) {
    const int kb = kc * 32 + quad * 8;
    bfx8 a = *(const bfx8*)(abase + kb);
#pragma unroll
    for (int j = 0; j < 6; ++j) {
      bfx8 bv = *(const bfx8*)(bbase + (size_t)(16 * j) * 8192 + kb);
      acc[j] = __builtin_amdgcn_mfma_f32_16x16x32_bf16(a, bv, acc[j], 0, 0, 0);
    }
  }
#pragma unroll
  for (int j = 0; j < 6; ++j) {
    int t = 16 * j + l15;
#pragma unroll
    for (int r = 0; r < 4; ++r) {
      int bm = bmw + quad * 4 + r;
      P[((size_t)ks * nbm + bm) * TTX + t] = acc[j][r];
    }
  }
}

__global__ __launch_bounds__(256) void head_reduce(
    const float* __restrict__ P, const float* __restrict__ hb,
    float* __restrict__ out, int nbm, int bm_off) {
  int i = blockIdx.x * 256 + threadIdx.x;    // nbm*96
  int t = i % TTX;
  int bm = i / TTX;
  float s = hb[t];
#pragma unroll
  for (int ks = 0; ks < 8; ++ks) s += P[((size_t)ks * nbm + bm) * TTX + t];
  out[(size_t)(bm_off + bm) * TTX + t] = s;
}

// ---------------------------------------------------------------------------
extern "C" void kernel_launch(void* const* d_in, const int* in_sizes, int n_in,
                              void* d_out, int out_size, void* d_ws, size_t ws_size,
                              hipStream_t stream) {
  const float* x      = (const float*)d_in[0];
  const float* emb_w  = (const float*)d_in[1];
  const float* emb_b  = (const float*)d_in[2];
  const float* head_w = (const float*)d_in[3];
  const float* head_b = (const float*)d_in[4];
  const float* dw_w1  = (const float*)d_in[5];
  const float* dw_b1  = (const float*)d_in[6];
  const float* f11_w  = (const float*)d_in[7];
  const float* f11_b  = (const float*)d_in[8];
  const float* f12_w  = (const float*)d_in[9];
  const float* f12_b  = (const float*)d_in[10];
  const float* dw_w2  = (const float*)d_in[11];
  const float* dw_b2  = (const float*)d_in[12];
  const float* f21_w  = (const float*)d_in[13];
  const float* f21_b  = (const float*)d_in[14];
  const float* f22_w  = (const float*)d_in[15];
  const float* f22_b  = (const float*)d_in[16];

  // fixed: 4 conv wT (98304 bf16 each) + hwT (786432 bf16)
  const size_t WEL = 98304, HWEL = 786432;
  __hip_bfloat16* wt11 = (__hip_bfloat16*)d_ws;
  __hip_bfloat16* wt12 = wt11 + WEL;
  __hip_bfloat16* wt21 = wt12 + WEL;
  __hip_bfloat16* wt22 = wt21 + WEL;
  __hip_bfloat16* hwT  = wt22 + WEL;
  char* dyn = (char*)(hwT + HWEL);
  const size_t fixed_bytes = (4 * WEL + HWEL) * 2;

  const size_t YP_B = (size_t)PROWS * PCOLS * DDX * 2;    // 1,114,880
  const size_t HP_B = (size_t)PROWS * PCOLS * RDX * 2;    // 2,229,760
  const size_t X_B  = (size_t)MMX * NNX * DDX * 4;        // 2,097,152
  const size_t XB_B = (size_t)MMX * NNX * DDX * 2;        // 1,048,576
  const size_t P_B  = (size_t)8 * MMX * TTX * 4;          //   196,608
  const size_t PER_B = YP_B + HP_B + X_B + XB_B + P_B;
  int Bc = 32;
  while (Bc > 1 && fixed_bytes + (size_t)Bc * PER_B > ws_size) Bc >>= 1;

  __hip_bfloat16* Yp = (__hip_bfloat16*)dyn;
  __hip_bfloat16* Hp = (__hip_bfloat16*)(dyn + (size_t)Bc * YP_B);
  float* X  = (float*)(dyn + (size_t)Bc * (YP_B + HP_B));
  __hip_bfloat16* Xb = (__hip_bfloat16*)(dyn + (size_t)Bc * (YP_B + HP_B + X_B));
  float* P  = (float*)(dyn + (size_t)Bc * (YP_B + HP_B + X_B + XB_B));
  const int nbm = Bc * MMX;

  // prep (once per launch)
  castw_kernel<<<384, 256, 0, stream>>>(f11_w, wt11, RDX, DDX);
  castw_kernel<<<384, 256, 0, stream>>>(f12_w, wt12, DDX, RDX);
  castw_kernel<<<384, 256, 0, stream>>>(f21_w, wt21, RDX, DDX);
  castw_kernel<<<384, 256, 0, stream>>>(f22_w, wt22, DDX, RDX);
  headw_kernel<<<3072, 256, 0, stream>>>(head_w, hwT);
  // zero padded halo buffers (ws is re-poisoned before every timed launch)
  hipMemsetAsync(Yp, 0, (size_t)Bc * (YP_B + HP_B), stream);

  for (int b0 = 0; b0 < 32; b0 += Bc) {
    int bm_off = b0 * MMX;
    embed_kernel<<<Bc * 2048, 256, 0, stream>>>(x, emb_w, emb_b, X, bm_off);

    for (int l = 0; l < 2; ++l) {
      const float* dwW = l ? dw_w2 : dw_w1;
      const float* dwB = l ? dw_b2 : dw_b1;
      const __hip_bfloat16* w1 = l ? wt21 : wt11;
      const float* b1 = l ? f21_b : f11_b;
      const __hip_bfloat16* w2 = l ? wt22 : wt12;
      const float* b2 = l ? f22_b : f12_b;

      dw_kernel<<<Bc * 32, 256, 0, stream>>>(X, dwW, dwB, Yp);
      conv_lds<DDX, RDX, true, 1>
          <<<Bc * MMX, 256, 0, stream>>>(Yp, w1, b1, Hp, nullptr, nullptr);
      conv_lds<RDX, DDX, false, 2>
          <<<Bc * MMX, 256, 0, stream>>>(Hp, w2, b2, nullptr, X, Xb);
    }

    head_split<<<Bc * 8, 256, 0, stream>>>(Xb, hwT, P, nbm);
    head_reduce<<<Bc * 24, 256, 0, stream>>>(P, head_b, (float*)d_out, nbm, bm_off);
  }
}

// Round 13
// 825.129 us; speedup vs baseline: 1.5493x; 1.0171x over previous
//
#include <hip/hip_runtime.h>
#include <hip/hip_bf16.h>
#include <math.h>

// dims
#define MMX 64
#define NNX 128
#define DDX 64
#define RDX 128
#define TTX 96
#define LLX 512
#define PROWS 67    // padded rows: m in [-1, 65]
#define PCOLS 130   // padded cols: n in [-1, 128]

typedef short bfx8 __attribute__((ext_vector_type(8)));
typedef float floatx4 __attribute__((ext_vector_type(4)));

__device__ __forceinline__ float gelu(float v) {
  return 0.5f * v * (1.0f + erff(v * 0.70710678118654752f));
}

// ---------------------------------------------------------------------------
// prep: conv weight fp32 [CO][CI][4][3] -> bf16 [dd=dm*3+dn][co][ci]
// ---------------------------------------------------------------------------
__global__ __launch_bounds__(256) void castw_kernel(
    const float* __restrict__ w, __hip_bfloat16* __restrict__ o, int CO, int CI) {
  int i = blockIdx.x * 256 + threadIdx.x;      // CO*CI*12 total
  int ci = i % CI;
  int t = i / CI;
  int co = t % CO;
  int dd = t / CO;
  o[i] = __float2bfloat16(w[(size_t)(co * CI + ci) * 12 + dd]);
}

// ---------------------------------------------------------------------------
// prep: head weight fp32 [96][f=d*128+n] -> bf16 [96][fh=n*64+d]
// ---------------------------------------------------------------------------
__global__ __launch_bounds__(256) void headw_kernel(
    const float* __restrict__ hw, __hip_bfloat16* __restrict__ o) {
  int i = blockIdx.x * 256 + threadIdx.x;      // 96*8192 total
  int fh = i & 8191;
  int t = i >> 13;
  int d = fh & 63;
  int n = fh >> 6;
  o[i] = __float2bfloat16(hw[(size_t)t * 8192 + d * 128 + n]);
}

// ---------------------------------------------------------------------------
// embed: x [B*M, L] fp32 -> X [Bc*M, N, D] fp32 (k=8 stride=4, edge-pad right)
// ---------------------------------------------------------------------------
__global__ __launch_bounds__(256) void embed_kernel(
    const float* __restrict__ x, const float* __restrict__ w,
    const float* __restrict__ bias, float* __restrict__ xe, int bm_off) {
  int tid = blockIdx.x * 256 + threadIdx.x;
  int d  = tid & 63;
  int n  = (tid >> 6) & 127;
  int bm = tid >> 13;
  const float* xr = x + (size_t)(bm_off + bm) * LLX;
  float acc = bias[d];
  int base = n * 4;
#pragma unroll
  for (int p = 0; p < 8; ++p) {
    int i = base + p;
    if (i > LLX - 1) i = LLX - 1;
    acc += w[d * 8 + p] * xr[i];
  }
  xe[tid] = acc;
}

// ---------------------------------------------------------------------------
// depthwise conv over M (k=4, zero-pad 1/2): X fp32 [b,m,n,d] -> Yp bf16 padded
// Rolling register window over m: X read ONCE.
// Yp layout [b][PROWS][PCOLS][64], interior at [m+1][n+1]; halos pre-zeroed.
// ---------------------------------------------------------------------------
__global__ __launch_bounds__(256) void dw_kernel(
    const float* __restrict__ xe, const float* __restrict__ w,
    const float* __restrict__ bias, __hip_bfloat16* __restrict__ yp) {
  const int tid = threadIdx.x;
  const int d = tid & 63;
  const int n = ((blockIdx.x & 31) << 2) + (tid >> 6);
  const int b = blockIdx.x >> 5;
  const int c = n * DDX + d;
  const float w0 = w[c * 4 + 0], w1 = w[c * 4 + 1];
  const float w2 = w[c * 4 + 2], w3 = w[c * 4 + 3];
  const float bv = bias[c];
  const float* src = xe + ((size_t)b * MMX * NNX + n) * DDX + d;
  __hip_bfloat16* dst = yp + (((size_t)b * PROWS + 1) * PCOLS + n + 1) * DDX + d;
  const int sstr = NNX * DDX;
  const int dstr = PCOLS * DDX;
  // taps: out[m] = w0*x[m-1] + w1*x[m] + w2*x[m+1] + w3*x[m+2], zero-pad
  float xm1 = 0.f, x0 = src[0], xp1 = src[sstr], xp2;
#pragma unroll 4
  for (int m = 0; m < MMX; ++m) {
    xp2 = (m + 2 < MMX) ? src[(size_t)(m + 2) * sstr] : 0.f;
    float acc = bv + w0 * xm1 + w1 * x0 + w2 * xp1 + w3 * xp2;
    dst[(size_t)m * dstr] = __float2bfloat16(acc);
    xm1 = x0; x0 = xp1; xp1 = xp2;
  }
}

// ---------------------------------------------------------------------------
// MFMA conv2d 4x3. Block = one (b,m). WPX waves along px x (4/WPX) along co.
//   conv1 (64->128): WPX=1 -> wave = 128px x 32co (CT=2, 2 Bf loads/phase)
//   conv2 (128->64): WPX=2 -> wave =  64px x 32co (CT=2)
// r11 FIX: __launch_bounds__(256, 4). r10 counters: without the 2nd arg the
// compiler allocated 64 VGPR (8-wave heuristic) and spilled st[] to scratch
// -- conv2 WRITE_SIZE 364MB (~260MB scratch, = st re-stored 4x/block),
// FETCH 296MB, MfmaUtil 11%, 184us. LDS (35.8KB -> 4 blocks/CU) already
// caps occupancy at 4 waves/SIMD, so cap VGPR at 512/4=128: demand
// (conv1 ~111, conv2 ~95) fits -> zero spill at identical occupancy.
// KEPT (r4): fully-unrolled epilogue -- compile-time acc indices (runtime-h
// indexing demoted acc to scratch: VGPR=84, 830MB scratch writes).
// KEPT (r7): co-split waves (r5's WPX=4/WCO=1 made every wave load ALL COUT
// weights: 8-dependent-load phases, MfmaUtil 7%); Bf per-(dn,kc) (8 VGPR
// live); single-a reads (4 VGPR live).
// T14 async-STAGE: dm+1 prefetch issued AFTER the post-staging barrier so it
// flies under this dm's MFMA phase (barriers drain vmcnt).
// XCD-swizzled (b,m). in padded [b][67][130][CIN]; wT [12][COUT][CIN].
// GELU: write Hp padded interior (bf16). else: X += resid (fp32) and Xb bf16.
// ---------------------------------------------------------------------------
template <int CIN, int COUT, bool GELU, int WPX>
__global__ __launch_bounds__(256, 4) void conv_lds(
    const __hip_bfloat16* __restrict__ in,
    const __hip_bfloat16* __restrict__ wT,
    const float* __restrict__ bias,
    __hip_bfloat16* __restrict__ hout,   // padded [b][67][130][COUT]
    float* xio,                          // [b][64][128][COUT] fp32
    __hip_bfloat16* __restrict__ xb) {   // [b][64][128][COUT] bf16
  constexpr int ASTR = CIN + 8;          // LDS row stride (2-way bank alias max)
  constexpr int KC = CIN / 32;           // k-chunks per (dm,dn)
  constexpr int WCO = 4 / WPX;           // waves along co
  constexpr int PT = 8 / WPX;            // 16-px tiles per wave
  constexpr int CT = COUT / 16 / WCO;    // 16-co tiles per wave (=2 both convs)
  constexpr int TOTCH = 130 * CIN / 8;   // uint4 chunks per padded row
  constexpr int PER = (TOTCH + 255) / 256;  // 5 (conv1) / 9 (conv2)
  __shared__ short smem[130 * ASTR];     // conv1 18.7 KB, conv2 35.4 KB

  // bijective XCD swizzle (grid = Bc*64, always %8==0)
  const int nwg = gridDim.x;
  const int wid = (blockIdx.x & 7) * (nwg >> 3) + (blockIdx.x >> 3);
  const int m = wid & 63;
  const int b = wid >> 6;
  const int tid = threadIdx.x;
  const int lane = tid & 63;
  const int w = tid >> 6;
  const int wco = w % WCO;
  const int wpx = w / WCO;
  const int wc0 = wco * (16 * CT);
  const int px0 = wpx * (16 * PT);
  const int l15 = lane & 15;
  const int quad = lane >> 4;

  floatx4 acc[PT][CT];
#pragma unroll
  for (int i = 0; i < PT; ++i)
#pragma unroll
    for (int j = 0; j < CT; ++j) acc[i][j] = (floatx4)0.f;

  const __hip_bfloat16* inrow = in + ((size_t)b * PROWS + m) * PCOLS * CIN;

  // prologue: issue dm=0 row loads into registers
  uint4 st[PER];
  {
    const uint4* src = (const uint4*)inrow;
#pragma unroll
    for (int p = 0; p < PER; ++p) {
      int idx = tid + p * 256;
      if (idx < TOTCH) st[p] = src[idx];
    }
  }

#pragma unroll 1
  for (int dm = 0; dm < 4; ++dm) {
    __syncthreads();  // (A) prior K-step smem reads done; drains prefetch
    // write already-landed staged regs -> LDS (pure lgkm)
#pragma unroll
    for (int p = 0; p < PER; ++p) {
      int idx = tid + p * 256;
      if (idx < TOTCH) {
        int col = idx / (CIN / 8), cg = idx % (CIN / 8);
        *(uint4*)&smem[col * ASTR + cg * 8] = st[p];
      }
    }
    __syncthreads();  // (B) staging visible

    // issue NEXT row's loads AFTER the barrier -> fly under this dm's MFMAs
    if (dm < 3) {
      const uint4* src = (const uint4*)(inrow + (size_t)(dm + 1) * PCOLS * CIN);
#pragma unroll
      for (int p = 0; p < PER; ++p) {
        int idx = tid + p * 256;
        if (idx < TOTCH) st[p] = src[idx];
      }
    }

    const __hip_bfloat16* wbase = wT + (size_t)dm * 3 * COUT * CIN;
#pragma unroll
    for (int dn = 0; dn < 3; ++dn) {
#pragma unroll
      for (int kc = 0; kc < KC; ++kc) {
        const int kb = kc * 32 + quad * 8;
        // B fragments for THIS (dn,kc) only (live range: CT=2 bfx8)
        bfx8 Bf[CT];
#pragma unroll
        for (int j = 0; j < CT; ++j)
          Bf[j] = *(const bfx8*)(
              wbase + ((size_t)dn * COUT + wc0 + 16 * j + l15) * CIN +
              kc * 32 + quad * 8);
#pragma unroll
        for (int i = 0; i < PT; ++i) {
          // A fragment per px-tile (live range: 1 bfx8; scheduler pipelines)
          bfx8 a = *(const bfx8*)&smem[(px0 + 16 * i + l15 + dn) * ASTR + kb];
#pragma unroll
          for (int j = 0; j < CT; ++j)
            acc[i][j] = __builtin_amdgcn_mfma_f32_16x16x32_bf16(
                a, Bf[j], acc[i][j], 0, 0, 0);
        }
      }
    }
  }

  // bias
  float bs[CT];
#pragma unroll
  for (int j = 0; j < CT; ++j) bs[j] = bias[wc0 + 16 * j + l15];

  // epilogue: LDS transpose per 64-px half -> coalesced wide stores.
  // FULLY UNROLLED over h (compile-time acc indices -- no scratch demotion).
  // Unified tile mapping: wave owns global 16-px tiles g = wpx*PT + i;
  // tile g belongs to half h iff g>>2 == h; row-in-half ii = g&3.
  __syncthreads();  // all K-loop smem reads done before reuse
#pragma unroll
  for (int h = 0; h < 2; ++h) {
    if (GELU) {
      constexpr int STR2 = COUT + 8;     // shorts
      short* t2 = smem;
#pragma unroll
      for (int i = 0; i < PT; ++i) {
        int g = wpx * PT + i;
        if ((g >> 2) == h) {
          int ii = g & 3;
#pragma unroll
          for (int j = 0; j < CT; ++j)
#pragma unroll
            for (int r = 0; r < 4; ++r) {
              int pl = 16 * ii + quad * 4 + r;
              __hip_bfloat16 bv = __float2bfloat16(gelu(acc[i][j][r] + bs[j]));
              t2[pl * STR2 + wc0 + 16 * j + l15] = *(short*)&bv;
            }
        }
      }
      __syncthreads();
      constexpr int CHUNKS = 64 * COUT / 8;   // 1024
      size_t gbase = (((size_t)b * PROWS + m + 1) * PCOLS + 1 + h * 64) * COUT;
      for (int idx = tid; idx < CHUNKS; idx += 256) {
        int px = idx / (COUT / 8), cg = idx % (COUT / 8);
        uint4 v = *(uint4*)&t2[px * STR2 + cg * 8];
        *(uint4*)(hout + gbase + (size_t)px * COUT + cg * 8) = v;
      }
      __syncthreads();
    } else {
      constexpr int STRF = COUT + 4;     // floats
      float* tf = (float*)smem;
#pragma unroll
      for (int i = 0; i < PT; ++i) {
        int g = wpx * PT + i;
        if ((g >> 2) == h) {
          int ii = g & 3;
#pragma unroll
          for (int j = 0; j < CT; ++j)
#pragma unroll
            for (int r = 0; r < 4; ++r) {
              int pl = 16 * ii + quad * 4 + r;
              tf[pl * STRF + wc0 + 16 * j + l15] = acc[i][j][r] + bs[j];
            }
        }
      }
      __syncthreads();
      constexpr int CHUNKS = 64 * COUT / 4;   // 1024
      size_t gbase = (((size_t)b * MMX + m) * NNX + h * 64) * COUT;
      for (int idx = tid; idx < CHUNKS; idx += 256) {
        int px = idx / (COUT / 4), cg = idx % (COUT / 4);
        float4 a4 = *(float4*)&tf[px * STRF + cg * 4];
        size_t gx = gbase + (size_t)px * COUT + cg * 4;
        float4 xv = *(float4*)(xio + gx);
        float4 rr = make_float4(a4.x + xv.x, a4.y + xv.y, a4.z + xv.z, a4.w + xv.w);
        *(float4*)(xio + gx) = rr;
        __hip_bfloat16 o0 = __float2bfloat16(rr.x), o1 = __float2bfloat16(rr.y);
        __hip_bfloat16 o2 = __float2bfloat16(rr.z), o3 = __float2bfloat16(rr.w);
        ushort4 ov = make_ushort4(*(unsigned short*)&o0, *(unsigned short*)&o1,
                                  *(unsigned short*)&o2, *(unsigned short*)&o3);
        *(ushort4*)(xb + gx) = ov;
      }
      __syncthreads();
    }
  }
}

// ---------------------------------------------------------------------------
// head split-K: P[ks][bm][t] = sum_{k in slice} Xb[bm][k] * hwT[t][k]
// grid = Bc * 8; block = 64 bm x 96 t x K=1024. 4 waves = 16 bm each.
// ---------------------------------------------------------------------------
__global__ __launch_bounds__(256) void head_split(
    const __hip_bfloat16* __restrict__ xb,   // [nbm][8192]
    const __hip_bfloat16* __restrict__ hwT,  // [96][8192]
    float* __restrict__ P, int nbm) {        // [8][nbm][96]
  const int ks = blockIdx.x & 7;
  const int bm0 = (blockIdx.x >> 3) * 64;
  const int lane = threadIdx.x & 63;
  const int w = threadIdx.x >> 6;
  const int l15 = lane & 15;
  const int quad = lane >> 4;
  const int bmw = bm0 + w * 16;

  floatx4 acc[6];
#pragma unroll
  for (int j = 0; j < 6; ++j) acc[j] = (floatx4)0.f;

  const int k0 = ks * 1024;
  const __hip_bfloat16* abase = xb + (size_t)(bmw + l15) * 8192 + k0;
  const __hip_bfloat16* bbase = hwT + (size_t)l15 * 8192 + k0;
#pragma unroll 4
  for (int kc = 0; kc < 32; ++kc) {
    const int kb = kc * 32 + quad * 8;
    bfx8 a = *(const bfx8*)(abase + kb);
#pragma unroll
    for (int j = 0; j < 6; ++j) {
      bfx8 bv = *(const bfx8*)(bbase + (size_t)(16 * j) * 8192 + kb);
      acc[j] = __builtin_amdgcn_mfma_f32_16x16x32_bf16(a, bv, acc[j], 0, 0, 0);
    }
  }
#pragma unroll
  for (int j = 0; j < 6; ++j) {
    int t = 16 * j + l15;
#pragma unroll
    for (int r = 0; r < 4; ++r) {
      int bm = bmw + quad * 4 + r;
      P[((size_t)ks * nbm + bm) * TTX + t] = acc[j][r];
    }
  }
}

__global__ __launch_bounds__(256) void head_reduce(
    const float* __restrict__ P, const float* __restrict__ hb,
    float* __restrict__ out, int nbm, int bm_off) {
  int i = blockIdx.x * 256 + threadIdx.x;    // nbm*96
  int t = i % TTX;
  int bm = i / TTX;
  float s = hb[t];
#pragma unroll
  for (int ks = 0; ks < 8; ++ks) s += P[((size_t)ks * nbm + bm) * TTX + t];
  out[(size_t)(bm_off + bm) * TTX + t] = s;
}

// ---------------------------------------------------------------------------
extern "C" void kernel_launch(void* const* d_in, const int* in_sizes, int n_in,
                              void* d_out, int out_size, void* d_ws, size_t ws_size,
                              hipStream_t stream) {
  const float* x      = (const float*)d_in[0];
  const float* emb_w  = (const float*)d_in[1];
  const float* emb_b  = (const float*)d_in[2];
  const float* head_w = (const float*)d_in[3];
  const float* head_b = (const float*)d_in[4];
  const float* dw_w1  = (const float*)d_in[5];
  const float* dw_b1  = (const float*)d_in[6];
  const float* f11_w  = (const float*)d_in[7];
  const float* f11_b  = (const float*)d_in[8];
  const float* f12_w  = (const float*)d_in[9];
  const float* f12_b  = (const float*)d_in[10];
  const float* dw_w2  = (const float*)d_in[11];
  const float* dw_b2  = (const float*)d_in[12];
  const float* f21_w  = (const float*)d_in[13];
  const float* f21_b  = (const float*)d_in[14];
  const float* f22_w  = (const float*)d_in[15];
  const float* f22_b  = (const float*)d_in[16];

  // fixed: 4 conv wT (98304 bf16 each) + hwT (786432 bf16)
  const size_t WEL = 98304, HWEL = 786432;
  __hip_bfloat16* wt11 = (__hip_bfloat16*)d_ws;
  __hip_bfloat16* wt12 = wt11 + WEL;
  __hip_bfloat16* wt21 = wt12 + WEL;
  __hip_bfloat16* wt22 = wt21 + WEL;
  __hip_bfloat16* hwT  = wt22 + WEL;
  char* dyn = (char*)(hwT + HWEL);
  const size_t fixed_bytes = (4 * WEL + HWEL) * 2;

  const size_t YP_B = (size_t)PROWS * PCOLS * DDX * 2;    // 1,114,880
  const size_t HP_B = (size_t)PROWS * PCOLS * RDX * 2;    // 2,229,760
  const size_t X_B  = (size_t)MMX * NNX * DDX * 4;        // 2,097,152
  const size_t XB_B = (size_t)MMX * NNX * DDX * 2;        // 1,048,576
  const size_t P_B  = (size_t)8 * MMX * TTX * 4;          //   196,608
  const size_t PER_B = YP_B + HP_B + X_B + XB_B + P_B;
  int Bc = 32;
  while (Bc > 1 && fixed_bytes + (size_t)Bc * PER_B > ws_size) Bc >>= 1;

  __hip_bfloat16* Yp = (__hip_bfloat16*)dyn;
  __hip_bfloat16* Hp = (__hip_bfloat16*)(dyn + (size_t)Bc * YP_B);
  float* X  = (float*)(dyn + (size_t)Bc * (YP_B + HP_B));
  __hip_bfloat16* Xb = (__hip_bfloat16*)(dyn + (size_t)Bc * (YP_B + HP_B + X_B));
  float* P  = (float*)(dyn + (size_t)Bc * (YP_B + HP_B + X_B + XB_B));
  const int nbm = Bc * MMX;

  // prep (once per launch)
  castw_kernel<<<384, 256, 0, stream>>>(f11_w, wt11, RDX, DDX);
  castw_kernel<<<384, 256, 0, stream>>>(f12_w, wt12, DDX, RDX);
  castw_kernel<<<384, 256, 0, stream>>>(f21_w, wt21, RDX, DDX);
  castw_kernel<<<384, 256, 0, stream>>>(f22_w, wt22, DDX, RDX);
  headw_kernel<<<3072, 256, 0, stream>>>(head_w, hwT);
  // zero padded halo buffers (ws is re-poisoned before every timed launch)
  hipMemsetAsync(Yp, 0, (size_t)Bc * (YP_B + HP_B), stream);

  for (int b0 = 0; b0 < 32; b0 += Bc) {
    int bm_off = b0 * MMX;
    embed_kernel<<<Bc * 2048, 256, 0, stream>>>(x, emb_w, emb_b, X, bm_off);

    for (int l = 0; l < 2; ++l) {
      const float* dwW = l ? dw_w2 : dw_w1;
      const float* dwB = l ? dw_b2 : dw_b1;
      const __hip_bfloat16* w1 = l ? wt21 : wt11;
      const float* b1 = l ? f21_b : f11_b;
      const __hip_bfloat16* w2 = l ? wt22 : wt12;
      const float* b2 = l ? f22_b : f12_b;

      dw_kernel<<<Bc * 32, 256, 0, stream>>>(X, dwW, dwB, Yp);
      conv_lds<DDX, RDX, true, 1>
          <<<Bc * MMX, 256, 0, stream>>>(Yp, w1, b1, Hp, nullptr, nullptr);
      conv_lds<RDX, DDX, false, 2>
          <<<Bc * MMX, 256, 0, stream>>>(Hp, w2, b2, nullptr, X, Xb);
    }

    head_split<<<Bc * 8, 256, 0, stream>>>(Xb, hwT, P, nbm);
    head_reduce<<<Bc * 24, 256, 0, stream>>>(P, head_b, (float*)d_out, nbm, bm_off);
  }
}

// Round 15
// 758.809 us; speedup vs baseline: 1.6847x; 1.0874x over previous
//
#include <hip/hip_runtime.h>
#include <hip/hip_bf16.h>
#include <math.h>

// dims
#define MMX 64
#define NNX 128
#define DDX 64
#define RDX 128
#define TTX 96
#define LLX 512
#define PROWS 67    // padded rows: m in [-1, 65]
#define PCOLS 130   // padded cols: n in [-1, 128]

typedef short bfx8 __attribute__((ext_vector_type(8)));
typedef float floatx4 __attribute__((ext_vector_type(4)));

__device__ __forceinline__ float gelu(float v) {
  return 0.5f * v * (1.0f + erff(v * 0.70710678118654752f));
}

// ---------------------------------------------------------------------------
// prep: conv weight fp32 [CO][CI][4][3] -> bf16 [dd=dm*3+dn][co][ci]
// ---------------------------------------------------------------------------
__global__ __launch_bounds__(256) void castw_kernel(
    const float* __restrict__ w, __hip_bfloat16* __restrict__ o, int CO, int CI) {
  int i = blockIdx.x * 256 + threadIdx.x;      // CO*CI*12 total
  int ci = i % CI;
  int t = i / CI;
  int co = t % CO;
  int dd = t / CO;
  o[i] = __float2bfloat16(w[(size_t)(co * CI + ci) * 12 + dd]);
}

// ---------------------------------------------------------------------------
// prep: head weight fp32 [96][f=d*128+n] -> bf16 [96][fh=n*64+d]
// ---------------------------------------------------------------------------
__global__ __launch_bounds__(256) void headw_kernel(
    const float* __restrict__ hw, __hip_bfloat16* __restrict__ o) {
  int i = blockIdx.x * 256 + threadIdx.x;      // 96*8192 total
  int fh = i & 8191;
  int t = i >> 13;
  int d = fh & 63;
  int n = fh >> 6;
  o[i] = __float2bfloat16(hw[(size_t)t * 8192 + d * 128 + n]);
}

// ---------------------------------------------------------------------------
// embed: x [B*M, L] fp32 -> X [Bc*M, N, D] fp32 (k=8 stride=4, edge-pad right)
// ---------------------------------------------------------------------------
__global__ __launch_bounds__(256) void embed_kernel(
    const float* __restrict__ x, const float* __restrict__ w,
    const float* __restrict__ bias, float* __restrict__ xe, int bm_off) {
  int tid = blockIdx.x * 256 + threadIdx.x;
  int d  = tid & 63;
  int n  = (tid >> 6) & 127;
  int bm = tid >> 13;
  const float* xr = x + (size_t)(bm_off + bm) * LLX;
  float acc = bias[d];
  int base = n * 4;
#pragma unroll
  for (int p = 0; p < 8; ++p) {
    int i = base + p;
    if (i > LLX - 1) i = LLX - 1;
    acc += w[d * 8 + p] * xr[i];
  }
  xe[tid] = acc;
}

// ---------------------------------------------------------------------------
// depthwise conv over M (k=4, zero-pad 1/2): X fp32 [b,m,n,d] -> Yp bf16 padded
// Rolling register window over m: X read ONCE.
// Yp layout [b][PROWS][PCOLS][64], interior at [m+1][n+1]; halos pre-zeroed.
// ---------------------------------------------------------------------------
__global__ __launch_bounds__(256) void dw_kernel(
    const float* __restrict__ xe, const float* __restrict__ w,
    const float* __restrict__ bias, __hip_bfloat16* __restrict__ yp) {
  const int tid = threadIdx.x;
  const int d = tid & 63;
  const int n = ((blockIdx.x & 31) << 2) + (tid >> 6);
  const int b = blockIdx.x >> 5;
  const int c = n * DDX + d;
  const float w0 = w[c * 4 + 0], w1 = w[c * 4 + 1];
  const float w2 = w[c * 4 + 2], w3 = w[c * 4 + 3];
  const float bv = bias[c];
  const float* src = xe + ((size_t)b * MMX * NNX + n) * DDX + d;
  __hip_bfloat16* dst = yp + (((size_t)b * PROWS + 1) * PCOLS + n + 1) * DDX + d;
  const int sstr = NNX * DDX;
  const int dstr = PCOLS * DDX;
  // taps: out[m] = w0*x[m-1] + w1*x[m] + w2*x[m+1] + w3*x[m+2], zero-pad
  float xm1 = 0.f, x0 = src[0], xp1 = src[sstr], xp2;
#pragma unroll 4
  for (int m = 0; m < MMX; ++m) {
    xp2 = (m + 2 < MMX) ? src[(size_t)(m + 2) * sstr] : 0.f;
    float acc = bv + w0 * xm1 + w1 * x0 + w2 * xp1 + w3 * xp2;
    dst[(size_t)m * dstr] = __float2bfloat16(acc);
    xm1 = x0; x0 = xp1; xp1 = xp2;
  }
}

// ---------------------------------------------------------------------------
// MFMA conv2d 4x3. Block = one (b,m). WPX waves along px x (4/WPX) along co.
//   conv1 (64->128): WPX=1 -> wave = 128px x 32co (CT=2, 2 Bf loads/phase)
//   conv2 (128->64): WPX=2 -> wave =  64px x 32co (CT=2)
// r14 FIX: amdgpu_waves_per_eu(4,4). r13 showed __launch_bounds__(256,4) is
// only a MIN-waves constraint (resource ceiling); the allocator's own
// heuristic still targeted 8 waves/EU -> 52 VGPR -> st[] spilled: WRITE_SIZE
// 364MB bit-identical to r10, MfmaUtil 11%, 185us. Pinning max waves/EU = 4
// tells the allocator to SPEND up to 128 VGPR (LDS already caps conv2 at 4
// blocks/CU, so no occupancy is lost). Demand: conv1 ~111, conv2 ~95.
// KEPT (r4): fully-unrolled epilogue -- compile-time acc indices (runtime-h
// indexing demoted acc to scratch: VGPR=84, 830MB scratch writes).
// KEPT (r7): co-split waves (r5's WPX=4/WCO=1 made every wave load ALL COUT
// weights: 8-dependent-load phases, MfmaUtil 7%); Bf per-(dn,kc) (8 VGPR
// live); single-a reads (4 VGPR live).
// T14 async-STAGE: dm+1 prefetch issued AFTER the post-staging barrier so it
// flies under this dm's MFMA phase (barriers drain vmcnt).
// XCD-swizzled (b,m). in padded [b][67][130][CIN]; wT [12][COUT][CIN].
// GELU: write Hp padded interior (bf16). else: X += resid (fp32) and Xb bf16.
// FALSIFICATION: if VGPR stays ~52 / WRITE stays 364MB, attributes can't
// steer this allocator -> next round restructures staging (halved st[]
// liveness or drop T14) to force demand under the 64-VGPR budget.
// ---------------------------------------------------------------------------
template <int CIN, int COUT, bool GELU, int WPX>
__global__ __launch_bounds__(256)
__attribute__((amdgpu_waves_per_eu(4, 4))) void conv_lds(
    const __hip_bfloat16* __restrict__ in,
    const __hip_bfloat16* __restrict__ wT,
    const float* __restrict__ bias,
    __hip_bfloat16* __restrict__ hout,   // padded [b][67][130][COUT]
    float* xio,                          // [b][64][128][COUT] fp32
    __hip_bfloat16* __restrict__ xb) {   // [b][64][128][COUT] bf16
  constexpr int ASTR = CIN + 8;          // LDS row stride (2-way bank alias max)
  constexpr int KC = CIN / 32;           // k-chunks per (dm,dn)
  constexpr int WCO = 4 / WPX;           // waves along co
  constexpr int PT = 8 / WPX;            // 16-px tiles per wave
  constexpr int CT = COUT / 16 / WCO;    // 16-co tiles per wave (=2 both convs)
  constexpr int TOTCH = 130 * CIN / 8;   // uint4 chunks per padded row
  constexpr int PER = (TOTCH + 255) / 256;  // 5 (conv1) / 9 (conv2)
  __shared__ short smem[130 * ASTR];     // conv1 18.7 KB, conv2 35.4 KB

  // bijective XCD swizzle (grid = Bc*64, always %8==0)
  const int nwg = gridDim.x;
  const int wid = (blockIdx.x & 7) * (nwg >> 3) + (blockIdx.x >> 3);
  const int m = wid & 63;
  const int b = wid >> 6;
  const int tid = threadIdx.x;
  const int lane = tid & 63;
  const int w = tid >> 6;
  const int wco = w % WCO;
  const int wpx = w / WCO;
  const int wc0 = wco * (16 * CT);
  const int px0 = wpx * (16 * PT);
  const int l15 = lane & 15;
  const int quad = lane >> 4;

  floatx4 acc[PT][CT];
#pragma unroll
  for (int i = 0; i < PT; ++i)
#pragma unroll
    for (int j = 0; j < CT; ++j) acc[i][j] = (floatx4)0.f;

  const __hip_bfloat16* inrow = in + ((size_t)b * PROWS + m) * PCOLS * CIN;

  // prologue: issue dm=0 row loads into registers
  uint4 st[PER];
  {
    const uint4* src = (const uint4*)inrow;
#pragma unroll
    for (int p = 0; p < PER; ++p) {
      int idx = tid + p * 256;
      if (idx < TOTCH) st[p] = src[idx];
    }
  }

#pragma unroll 1
  for (int dm = 0; dm < 4; ++dm) {
    __syncthreads();  // (A) prior K-step smem reads done; drains prefetch
    // write already-landed staged regs -> LDS (pure lgkm)
#pragma unroll
    for (int p = 0; p < PER; ++p) {
      int idx = tid + p * 256;
      if (idx < TOTCH) {
        int col = idx / (CIN / 8), cg = idx % (CIN / 8);
        *(uint4*)&smem[col * ASTR + cg * 8] = st[p];
      }
    }
    __syncthreads();  // (B) staging visible

    // issue NEXT row's loads AFTER the barrier -> fly under this dm's MFMAs
    if (dm < 3) {
      const uint4* src = (const uint4*)(inrow + (size_t)(dm + 1) * PCOLS * CIN);
#pragma unroll
      for (int p = 0; p < PER; ++p) {
        int idx = tid + p * 256;
        if (idx < TOTCH) st[p] = src[idx];
      }
    }

    const __hip_bfloat16* wbase = wT + (size_t)dm * 3 * COUT * CIN;
#pragma unroll
    for (int dn = 0; dn < 3; ++dn) {
#pragma unroll
      for (int kc = 0; kc < KC; ++kc) {
        const int kb = kc * 32 + quad * 8;
        // B fragments for THIS (dn,kc) only (live range: CT=2 bfx8)
        bfx8 Bf[CT];
#pragma unroll
        for (int j = 0; j < CT; ++j)
          Bf[j] = *(const bfx8*)(
              wbase + ((size_t)dn * COUT + wc0 + 16 * j + l15) * CIN +
              kc * 32 + quad * 8);
#pragma unroll
        for (int i = 0; i < PT; ++i) {
          // A fragment per px-tile (live range: 1 bfx8; scheduler pipelines)
          bfx8 a = *(const bfx8*)&smem[(px0 + 16 * i + l15 + dn) * ASTR + kb];
#pragma unroll
          for (int j = 0; j < CT; ++j)
            acc[i][j] = __builtin_amdgcn_mfma_f32_16x16x32_bf16(
                a, Bf[j], acc[i][j], 0, 0, 0);
        }
      }
    }
  }

  // bias
  float bs[CT];
#pragma unroll
  for (int j = 0; j < CT; ++j) bs[j] = bias[wc0 + 16 * j + l15];

  // epilogue: LDS transpose per 64-px half -> coalesced wide stores.
  // FULLY UNROLLED over h (compile-time acc indices -- no scratch demotion).
  // Unified tile mapping: wave owns global 16-px tiles g = wpx*PT + i;
  // tile g belongs to half h iff g>>2 == h; row-in-half ii = g&3.
  __syncthreads();  // all K-loop smem reads done before reuse
#pragma unroll
  for (int h = 0; h < 2; ++h) {
    if (GELU) {
      constexpr int STR2 = COUT + 8;     // shorts
      short* t2 = smem;
#pragma unroll
      for (int i = 0; i < PT; ++i) {
        int g = wpx * PT + i;
        if ((g >> 2) == h) {
          int ii = g & 3;
#pragma unroll
          for (int j = 0; j < CT; ++j)
#pragma unroll
            for (int r = 0; r < 4; ++r) {
              int pl = 16 * ii + quad * 4 + r;
              __hip_bfloat16 bv = __float2bfloat16(gelu(acc[i][j][r] + bs[j]));
              t2[pl * STR2 + wc0 + 16 * j + l15] = *(short*)&bv;
            }
        }
      }
      __syncthreads();
      constexpr int CHUNKS = 64 * COUT / 8;   // 1024
      size_t gbase = (((size_t)b * PROWS + m + 1) * PCOLS + 1 + h * 64) * COUT;
      for (int idx = tid; idx < CHUNKS; idx += 256) {
        int px = idx / (COUT / 8), cg = idx % (COUT / 8);
        uint4 v = *(uint4*)&t2[px * STR2 + cg * 8];
        *(uint4*)(hout + gbase + (size_t)px * COUT + cg * 8) = v;
      }
      __syncthreads();
    } else {
      constexpr int STRF = COUT + 4;     // floats
      float* tf = (float*)smem;
#pragma unroll
      for (int i = 0; i < PT; ++i) {
        int g = wpx * PT + i;
        if ((g >> 2) == h) {
          int ii = g & 3;
#pragma unroll
          for (int j = 0; j < CT; ++j)
#pragma unroll
            for (int r = 0; r < 4; ++r) {
              int pl = 16 * ii + quad * 4 + r;
              tf[pl * STRF + wc0 + 16 * j + l15] = acc[i][j][r] + bs[j];
            }
        }
      }
      __syncthreads();
      constexpr int CHUNKS = 64 * COUT / 4;   // 1024
      size_t gbase = (((size_t)b * MMX + m) * NNX + h * 64) * COUT;
      for (int idx = tid; idx < CHUNKS; idx += 256) {
        int px = idx / (COUT / 4), cg = idx % (COUT / 4);
        float4 a4 = *(float4*)&tf[px * STRF + cg * 4];
        size_t gx = gbase + (size_t)px * COUT + cg * 4;
        float4 xv = *(float4*)(xio + gx);
        float4 rr = make_float4(a4.x + xv.x, a4.y + xv.y, a4.z + xv.z, a4.w + xv.w);
        *(float4*)(xio + gx) = rr;
        __hip_bfloat16 o0 = __float2bfloat16(rr.x), o1 = __float2bfloat16(rr.y);
        __hip_bfloat16 o2 = __float2bfloat16(rr.z), o3 = __float2bfloat16(rr.w);
        ushort4 ov = make_ushort4(*(unsigned short*)&o0, *(unsigned short*)&o1,
                                  *(unsigned short*)&o2, *(unsigned short*)&o3);
        *(ushort4*)(xb + gx) = ov;
      }
      __syncthreads();
    }
  }
}

// ---------------------------------------------------------------------------
// head split-K: P[ks][bm][t] = sum_{k in slice} Xb[bm][k] * hwT[t][k]
// grid = Bc * 8; block = 64 bm x 96 t x K=1024. 4 waves = 16 bm each.
// ---------------------------------------------------------------------------
__global__ __launch_bounds__(256) void head_split(
    const __hip_bfloat16* __restrict__ xb,   // [nbm][8192]
    const __hip_bfloat16* __restrict__ hwT,  // [96][8192]
    float* __restrict__ P, int nbm) {        // [8][nbm][96]
  const int ks = blockIdx.x & 7;
  const int bm0 = (blockIdx.x >> 3) * 64;
  const int lane = threadIdx.x & 63;
  const int w = threadIdx.x >> 6;
  const int l15 = lane & 15;
  const int quad = lane >> 4;
  const int bmw = bm0 + w * 16;

  floatx4 acc[6];
#pragma unroll
  for (int j = 0; j < 6; ++j) acc[j] = (floatx4)0.f;

  const int k0 = ks * 1024;
  const __hip_bfloat16* abase = xb + (size_t)(bmw + l15) * 8192 + k0;
  const __hip_bfloat16* bbase = hwT + (size_t)l15 * 8192 + k0;
#pragma unroll 4
  for (int kc = 0; kc < 32; ++kc) {
    const int kb = kc * 32 + quad * 8;
    bfx8 a = *(const bfx8*)(abase + kb);
#pragma unroll
    for (int j = 0; j < 6; ++j) {
      bfx8 bv = *(const bfx8*)(bbase + (size_t)(16 * j) * 8192 + kb);
      acc[j] = __builtin_amdgcn_mfma_f32_16x16x32_bf16(a, bv, acc[j], 0, 0, 0);
    }
  }
#pragma unroll
  for (int j = 0; j < 6; ++j) {
    int t = 16 * j + l15;
#pragma unroll
    for (int r = 0; r < 4; ++r) {
      int bm = bmw + quad * 4 + r;
      P[((size_t)ks * nbm + bm) * TTX + t] = acc[j][r];
    }
  }
}

__global__ __launch_bounds__(256) void head_reduce(
    const float* __restrict__ P, const float* __restrict__ hb,
    float* __restrict__ out, int nbm, int bm_off) {
  int i = blockIdx.x * 256 + threadIdx.x;    // nbm*96
  int t = i % TTX;
  int bm = i / TTX;
  float s = hb[t];
#pragma unroll
  for (int ks = 0; ks < 8; ++ks) s += P[((size_t)ks * nbm + bm) * TTX + t];
  out[(size_t)(bm_off + bm) * TTX + t] = s;
}

// ---------------------------------------------------------------------------
extern "C" void kernel_launch(void* const* d_in, const int* in_sizes, int n_in,
                              void* d_out, int out_size, void* d_ws, size_t ws_size,
                              hipStream_t stream) {
  const float* x      = (const float*)d_in[0];
  const float* emb_w  = (const float*)d_in[1];
  const float* emb_b  = (const float*)d_in[2];
  const float* head_w = (const float*)d_in[3];
  const float* head_b = (const float*)d_in[4];
  const float* dw_w1  = (const float*)d_in[5];
  const float* dw_b1  = (const float*)d_in[6];
  const float* f11_w  = (const float*)d_in[7];
  const float* f11_b  = (const float*)d_in[8];
  const float* f12_w  = (const float*)d_in[9];
  const float* f12_b  = (const float*)d_in[10];
  const float* dw_w2  = (const float*)d_in[11];
  const float* dw_b2  = (const float*)d_in[12];
  const float* f21_w  = (const float*)d_in[13];
  const float* f21_b  = (const float*)d_in[14];
  const float* f22_w  = (const float*)d_in[15];
  const float* f22_b  = (const float*)d_in[16];

  // fixed: 4 conv wT (98304 bf16 each) + hwT (786432 bf16)
  const size_t WEL = 98304, HWEL = 786432;
  __hip_bfloat16* wt11 = (__hip_bfloat16*)d_ws;
  __hip_bfloat16* wt12 = wt11 + WEL;
  __hip_bfloat16* wt21 = wt12 + WEL;
  __hip_bfloat16* wt22 = wt21 + WEL;
  __hip_bfloat16* hwT  = wt22 + WEL;
  char* dyn = (char*)(hwT + HWEL);
  const size_t fixed_bytes = (4 * WEL + HWEL) * 2;

  const size_t YP_B = (size_t)PROWS * PCOLS * DDX * 2;    // 1,114,880
  const size_t HP_B = (size_t)PROWS * PCOLS * RDX * 2;    // 2,229,760
  const size_t X_B  = (size_t)MMX * NNX * DDX * 4;        // 2,097,152
  const size_t XB_B = (size_t)MMX * NNX * DDX * 2;        // 1,048,576
  const size_t P_B  = (size_t)8 * MMX * TTX * 4;          //   196,608
  const size_t PER_B = YP_B + HP_B + X_B + XB_B + P_B;
  int Bc = 32;
  while (Bc > 1 && fixed_bytes + (size_t)Bc * PER_B > ws_size) Bc >>= 1;

  __hip_bfloat16* Yp = (__hip_bfloat16*)dyn;
  __hip_bfloat16* Hp = (__hip_bfloat16*)(dyn + (size_t)Bc * YP_B);
  float* X  = (float*)(dyn + (size_t)Bc * (YP_B + HP_B));
  __hip_bfloat16* Xb = (__hip_bfloat16*)(dyn + (size_t)Bc * (YP_B + HP_B + X_B));
  float* P  = (float*)(dyn + (size_t)Bc * (YP_B + HP_B + X_B + XB_B));
  const int nbm = Bc * MMX;

  // prep (once per launch)
  castw_kernel<<<384, 256, 0, stream>>>(f11_w, wt11, RDX, DDX);
  castw_kernel<<<384, 256, 0, stream>>>(f12_w, wt12, DDX, RDX);
  castw_kernel<<<384, 256, 0, stream>>>(f21_w, wt21, RDX, DDX);
  castw_kernel<<<384, 256, 0, stream>>>(f22_w, wt22, DDX, RDX);
  headw_kernel<<<3072, 256, 0, stream>>>(head_w, hwT);
  // zero padded halo buffers (ws is re-poisoned before every timed launch)
  hipMemsetAsync(Yp, 0, (size_t)Bc * (YP_B + HP_B), stream);

  for (int b0 = 0; b0 < 32; b0 += Bc) {
    int bm_off = b0 * MMX;
    embed_kernel<<<Bc * 2048, 256, 0, stream>>>(x, emb_w, emb_b, X, bm_off);

    for (int l = 0; l < 2; ++l) {
      const float* dwW = l ? dw_w2 : dw_w1;
      const float* dwB = l ? dw_b2 : dw_b1;
      const __hip_bfloat16* w1 = l ? wt21 : wt11;
      const float* b1 = l ? f21_b : f11_b;
      const __hip_bfloat16* w2 = l ? wt22 : wt12;
      const float* b2 = l ? f22_b : f12_b;

      dw_kernel<<<Bc * 32, 256, 0, stream>>>(X, dwW, dwB, Yp);
      conv_lds<DDX, RDX, true, 1>
          <<<Bc * MMX, 256, 0, stream>>>(Yp, w1, b1, Hp, nullptr, nullptr);
      conv_lds<RDX, DDX, false, 2>
          <<<Bc * MMX, 256, 0, stream>>>(Hp, w2, b2, nullptr, X, Xb);
    }

    head_split<<<Bc * 8, 256, 0, stream>>>(Xb, hwT, P, nbm);
    head_reduce<<<Bc * 24, 256, 0, stream>>>(P, head_b, (float*)d_out, nbm, bm_off);
  }
}

// Round 17
// 648.515 us; speedup vs baseline: 1.9712x; 1.1701x over previous
//
#include <hip/hip_runtime.h>
#include <hip/hip_bf16.h>
#include <math.h>

// dims
#define MMX 64
#define NNX 128
#define DDX 64
#define RDX 128
#define TTX 96
#define LLX 512
#define PROWS 67    // padded rows: m in [-1, 65]
#define PCOLS 130   // padded cols: n in [-1, 128]

typedef short bfx8 __attribute__((ext_vector_type(8)));
typedef float floatx4 __attribute__((ext_vector_type(4)));

__device__ __forceinline__ float gelu(float v) {
  return 0.5f * v * (1.0f + erff(v * 0.70710678118654752f));
}

// async global->LDS DMA, 16B per lane (dest = wave-uniform base + lane*16)
__device__ __forceinline__ void gload_lds16(const void* g, void* l) {
  __builtin_amdgcn_global_load_lds(
      (const __attribute__((address_space(1))) unsigned int*)g,
      (__attribute__((address_space(3))) unsigned int*)l, 16, 0, 0);
}

// ---------------------------------------------------------------------------
// prep: conv weight fp32 [CO][CI][4][3] -> bf16 [dd=dm*3+dn][co][ci]
// ---------------------------------------------------------------------------
__global__ __launch_bounds__(256) void castw_kernel(
    const float* __restrict__ w, __hip_bfloat16* __restrict__ o, int CO, int CI) {
  int i = blockIdx.x * 256 + threadIdx.x;      // CO*CI*12 total
  int ci = i % CI;
  int t = i / CI;
  int co = t % CO;
  int dd = t / CO;
  o[i] = __float2bfloat16(w[(size_t)(co * CI + ci) * 12 + dd]);
}

// ---------------------------------------------------------------------------
// prep: head weight fp32 [96][f=d*128+n] -> bf16 [96][fh=n*64+d]
// ---------------------------------------------------------------------------
__global__ __launch_bounds__(256) void headw_kernel(
    const float* __restrict__ hw, __hip_bfloat16* __restrict__ o) {
  int i = blockIdx.x * 256 + threadIdx.x;      // 96*8192 total
  int fh = i & 8191;
  int t = i >> 13;
  int d = fh & 63;
  int n = fh >> 6;
  o[i] = __float2bfloat16(hw[(size_t)t * 8192 + d * 128 + n]);
}

// ---------------------------------------------------------------------------
// embed: x [B*M, L] fp32 -> X [Bc*M, N, D] fp32 (k=8 stride=4, edge-pad right)
// ---------------------------------------------------------------------------
__global__ __launch_bounds__(256) void embed_kernel(
    const float* __restrict__ x, const float* __restrict__ w,
    const float* __restrict__ bias, float* __restrict__ xe, int bm_off) {
  int tid = blockIdx.x * 256 + threadIdx.x;
  int d  = tid & 63;
  int n  = (tid >> 6) & 127;
  int bm = tid >> 13;
  const float* xr = x + (size_t)(bm_off + bm) * LLX;
  float acc = bias[d];
  int base = n * 4;
#pragma unroll
  for (int p = 0; p < 8; ++p) {
    int i = base + p;
    if (i > LLX - 1) i = LLX - 1;
    acc += w[d * 8 + p] * xr[i];
  }
  xe[tid] = acc;
}

// ---------------------------------------------------------------------------
// depthwise conv over M (k=4, zero-pad 1/2): X fp32 [b,m,n,d] -> Yp bf16 padded
// Rolling register window over m: X read ONCE.
// Yp layout [b][PROWS][PCOLS][64], interior at [m+1][n+1]; halos pre-zeroed.
// ---------------------------------------------------------------------------
__global__ __launch_bounds__(256) void dw_kernel(
    const float* __restrict__ xe, const float* __restrict__ w,
    const float* __restrict__ bias, __hip_bfloat16* __restrict__ yp) {
  const int tid = threadIdx.x;
  const int d = tid & 63;
  const int n = ((blockIdx.x & 31) << 2) + (tid >> 6);
  const int b = blockIdx.x >> 5;
  const int c = n * DDX + d;
  const float w0 = w[c * 4 + 0], w1 = w[c * 4 + 1];
  const float w2 = w[c * 4 + 2], w3 = w[c * 4 + 3];
  const float bv = bias[c];
  const float* src = xe + ((size_t)b * MMX * NNX + n) * DDX + d;
  __hip_bfloat16* dst = yp + (((size_t)b * PROWS + 1) * PCOLS + n + 1) * DDX + d;
  const int sstr = NNX * DDX;
  const int dstr = PCOLS * DDX;
  // taps: out[m] = w0*x[m-1] + w1*x[m] + w2*x[m+1] + w3*x[m+2], zero-pad
  float xm1 = 0.f, x0 = src[0], xp1 = src[sstr], xp2;
#pragma unroll 4
  for (int m = 0; m < MMX; ++m) {
    xp2 = (m + 2 < MMX) ? src[(size_t)(m + 2) * sstr] : 0.f;
    float acc = bv + w0 * xm1 + w1 * x0 + w2 * xp1 + w3 * xp2;
    dst[(size_t)m * dstr] = __float2bfloat16(acc);
    xm1 = x0; x0 = xp1; xp1 = xp2;
  }
}

// ---------------------------------------------------------------------------
// MFMA conv2d 4x3. Block = one (b,m). WPX waves along px x (4/WPX) along co.
//   conv1 (64->128): WPX=1 -> wave = 128px x 32co (CT=2)
//   conv2 (128->64): WPX=2 -> wave =  64px x 32co (CT=2)
// r16 FIX: staging via __builtin_amdgcn_global_load_lds width=16 -- the
// register prefetch st[] is DELETED. r10/r13/r15: allocator pinned 52-64
// VGPR regardless of __launch_bounds__(256,4) (r13) and waves_per_eu(4,4)
// (r15, counters bit-identical) -> st[] spilled ~260MB/dispatch scratch
// (WRITE 364MB vs ~100 true, MfmaUtil 11%, 183us). DMA staging holds ZERO
// VGPRs -> nothing left to spill (demand: conv1 ~90, conv2 ~56).
// global_load_lds writes LINEARLY (wave-uniform base + lane*16; padding
// breaks it) -> LDS is now linear [130][CIN] and bank conflicts are fixed
// by a both-sides XOR swizzle (rule #21): source chunk c^(r&(NS-1)) on the
// DMA, same XOR on the ds_read slot. Reads hit all 32 banks at the
// 8-dword/bank floor (old +8 padding only used even banks).
// Loop: barrier(A) -> issue DMA row dm -> barrier(B, drains vmcnt) ->
// MFMA. Cross-block waves (4 blocks/CU) hide the DMA drain (m97 pattern).
// KEPT (r4): fully-unrolled epilogue (compile-time acc indices).
// KEPT (r7): co-split waves; Bf per-(dn,kc); single-a reads.
// XCD-swizzled (b,m). in padded [b][67][130][CIN]; wT [12][COUT][CIN].
// GELU: write Hp padded interior (bf16). else: X += resid (fp32) and Xb bf16.
// POST-MORTEM KEY: conv2 WRITE->~100MB & conv1 WRITE still inflated would
// mean conv1's acc(64 VGPR) still spills under a 64-VGPR budget -> next
// lever is conv1 WPX=2 (acc 32) or dm-loop split.
// ---------------------------------------------------------------------------
template <int CIN, int COUT, bool GELU, int WPX>
__global__ __launch_bounds__(256) void conv_lds(
    const __hip_bfloat16* __restrict__ in,
    const __hip_bfloat16* __restrict__ wT,
    const float* __restrict__ bias,
    __hip_bfloat16* __restrict__ hout,   // padded [b][67][130][COUT]
    float* xio,                          // [b][64][128][COUT] fp32
    __hip_bfloat16* __restrict__ xb) {   // [b][64][128][COUT] bf16
  constexpr int KC = CIN / 32;           // k-chunks per (dm,dn)
  constexpr int WCO = 4 / WPX;           // waves along co
  constexpr int PT = 8 / WPX;            // 16-px tiles per wave
  constexpr int CT = COUT / 16 / WCO;    // 16-co tiles per wave (=2 both convs)
  constexpr int NS = CIN / 8;            // 16B chunks per row
  constexpr int TOTCH = 130 * NS;        // 16B chunks per padded row-line
  constexpr int PER = (TOTCH + 255) / 256;  // 5 (conv1) / 9 (conv2)
  // smem: linear A-tile [130][CIN] shorts; epilogue scratch may be larger
  constexpr int EPI = GELU ? 64 * (COUT + 8) : 64 * (COUT + 4) * 2;  // shorts
  constexpr int SMEMN = (130 * CIN > EPI) ? 130 * CIN : EPI;
  __shared__ short smem[SMEMN];          // conv1 17.4 KB, conv2 33.3 KB

  // bijective XCD swizzle (grid = Bc*64, always %8==0)
  const int nwg = gridDim.x;
  const int wid = (blockIdx.x & 7) * (nwg >> 3) + (blockIdx.x >> 3);
  const int m = wid & 63;
  const int b = wid >> 6;
  const int tid = threadIdx.x;
  const int lane = tid & 63;
  const int w = tid >> 6;
  const int wco = w % WCO;
  const int wpx = w / WCO;
  const int wc0 = wco * (16 * CT);
  const int px0 = wpx * (16 * PT);
  const int l15 = lane & 15;
  const int quad = lane >> 4;

  floatx4 acc[PT][CT];
#pragma unroll
  for (int i = 0; i < PT; ++i)
#pragma unroll
    for (int j = 0; j < CT; ++j) acc[i][j] = (floatx4)0.f;

  const __hip_bfloat16* inrow = in + ((size_t)b * PROWS + m) * PCOLS * CIN;

#pragma unroll 1
  for (int dm = 0; dm < 4; ++dm) {
    __syncthreads();  // (A) prior K-step smem reads done before DMA overwrite
    // DMA row (m+dm) -> smem linear, XOR-swizzled SOURCE (zero VGPR held)
    {
      const __hip_bfloat16* rowp = inrow + (size_t)dm * PCOLS * CIN;
#pragma unroll
      for (int p = 0; p < PER; ++p) {
        int s = tid + p * 256;
        if (s < TOTCH) {
          int r = s / NS, c = s % NS;
          int cs = c ^ (r & (NS - 1));
          gload_lds16(rowp + (size_t)r * CIN + cs * 8, smem + s * 8);
        }
      }
    }
    __syncthreads();  // (B) drains vmcnt -> staged row visible

    const __hip_bfloat16* wbase = wT + (size_t)dm * 3 * COUT * CIN;
#pragma unroll
    for (int dn = 0; dn < 3; ++dn) {
#pragma unroll
      for (int kc = 0; kc < KC; ++kc) {
        // B fragments for THIS (dn,kc) only (live range: CT=2 bfx8)
        bfx8 Bf[CT];
#pragma unroll
        for (int j = 0; j < CT; ++j)
          Bf[j] = *(const bfx8*)(
              wbase + ((size_t)dn * COUT + wc0 + 16 * j + l15) * CIN +
              kc * 32 + quad * 8);
#pragma unroll
        for (int i = 0; i < PT; ++i) {
          // A fragment: row-major linear + XOR-swizzled slot (matches DMA)
          const int rowa = px0 + 16 * i + l15 + dn;
          const int slot = kc * 4 + quad;
          bfx8 a = *(const bfx8*)&smem[rowa * CIN +
                                       ((slot ^ (rowa & (NS - 1))) << 3)];
#pragma unroll
          for (int j = 0; j < CT; ++j)
            acc[i][j] = __builtin_amdgcn_mfma_f32_16x16x32_bf16(
                a, Bf[j], acc[i][j], 0, 0, 0);
        }
      }
    }
  }

  // bias
  float bs[CT];
#pragma unroll
  for (int j = 0; j < CT; ++j) bs[j] = bias[wc0 + 16 * j + l15];

  // epilogue: LDS transpose per 64-px half -> coalesced wide stores.
  // FULLY UNROLLED over h (compile-time acc indices -- no scratch demotion).
  // Unified tile mapping: wave owns global 16-px tiles g = wpx*PT + i;
  // tile g belongs to half h iff g>>2 == h; row-in-half ii = g&3.
  __syncthreads();  // all K-loop smem reads done before reuse
#pragma unroll
  for (int h = 0; h < 2; ++h) {
    if (GELU) {
      constexpr int STR2 = COUT + 8;     // shorts
      short* t2 = smem;
#pragma unroll
      for (int i = 0; i < PT; ++i) {
        int g = wpx * PT + i;
        if ((g >> 2) == h) {
          int ii = g & 3;
#pragma unroll
          for (int j = 0; j < CT; ++j)
#pragma unroll
            for (int r = 0; r < 4; ++r) {
              int pl = 16 * ii + quad * 4 + r;
              __hip_bfloat16 bv = __float2bfloat16(gelu(acc[i][j][r] + bs[j]));
              t2[pl * STR2 + wc0 + 16 * j + l15] = *(short*)&bv;
            }
        }
      }
      __syncthreads();
      constexpr int CHUNKS = 64 * COUT / 8;   // 1024
      size_t gbase = (((size_t)b * PROWS + m + 1) * PCOLS + 1 + h * 64) * COUT;
      for (int idx = tid; idx < CHUNKS; idx += 256) {
        int px = idx / (COUT / 8), cg = idx % (COUT / 8);
        uint4 v = *(uint4*)&t2[px * STR2 + cg * 8];
        *(uint4*)(hout + gbase + (size_t)px * COUT + cg * 8) = v;
      }
      __syncthreads();
    } else {
      constexpr int STRF = COUT + 4;     // floats
      float* tf = (float*)smem;
#pragma unroll
      for (int i = 0; i < PT; ++i) {
        int g = wpx * PT + i;
        if ((g >> 2) == h) {
          int ii = g & 3;
#pragma unroll
          for (int j = 0; j < CT; ++j)
#pragma unroll
            for (int r = 0; r < 4; ++r) {
              int pl = 16 * ii + quad * 4 + r;
              tf[pl * STRF + wc0 + 16 * j + l15] = acc[i][j][r] + bs[j];
            }
        }
      }
      __syncthreads();
      constexpr int CHUNKS = 64 * COUT / 4;   // 1024
      size_t gbase = (((size_t)b * MMX + m) * NNX + h * 64) * COUT;
      for (int idx = tid; idx < CHUNKS; idx += 256) {
        int px = idx / (COUT / 4), cg = idx % (COUT / 4);
        float4 a4 = *(float4*)&tf[px * STRF + cg * 4];
        size_t gx = gbase + (size_t)px * COUT + cg * 4;
        float4 xv = *(float4*)(xio + gx);
        float4 rr = make_float4(a4.x + xv.x, a4.y + xv.y, a4.z + xv.z, a4.w + xv.w);
        *(float4*)(xio + gx) = rr;
        __hip_bfloat16 o0 = __float2bfloat16(rr.x), o1 = __float2bfloat16(rr.y);
        __hip_bfloat16 o2 = __float2bfloat16(rr.z), o3 = __float2bfloat16(rr.w);
        ushort4 ov = make_ushort4(*(unsigned short*)&o0, *(unsigned short*)&o1,
                                  *(unsigned short*)&o2, *(unsigned short*)&o3);
        *(ushort4*)(xb + gx) = ov;
      }
      __syncthreads();
    }
  }
}

// ---------------------------------------------------------------------------
// head split-K: P[ks][bm][t] = sum_{k in slice} Xb[bm][k] * hwT[t][k]
// grid = Bc * 8; block = 64 bm x 96 t x K=1024. 4 waves = 16 bm each.
// ---------------------------------------------------------------------------
__global__ __launch_bounds__(256) void head_split(
    const __hip_bfloat16* __restrict__ xb,   // [nbm][8192]
    const __hip_bfloat16* __restrict__ hwT,  // [96][8192]
    float* __restrict__ P, int nbm) {        // [8][nbm][96]
  const int ks = blockIdx.x & 7;
  const int bm0 = (blockIdx.x >> 3) * 64;
  const int lane = threadIdx.x & 63;
  const int w = threadIdx.x >> 6;
  const int l15 = lane & 15;
  const int quad = lane >> 4;
  const int bmw = bm0 + w * 16;

  floatx4 acc[6];
#pragma unroll
  for (int j = 0; j < 6; ++j) acc[j] = (floatx4)0.f;

  const int k0 = ks * 1024;
  const __hip_bfloat16* abase = xb + (size_t)(bmw + l15) * 8192 + k0;
  const __hip_bfloat16* bbase = hwT + (size_t)l15 * 8192 + k0;
#pragma unroll 4
  for (int kc = 0; kc < 32; ++kc) {
    const int kb = kc * 32 + quad * 8;
    bfx8 a = *(const bfx8*)(abase + kb);
#pragma unroll
    for (int j = 0; j < 6; ++j) {
      bfx8 bv = *(const bfx8*)(bbase + (size_t)(16 * j) * 8192 + kb);
      acc[j] = __builtin_amdgcn_mfma_f32_16x16x32_bf16(a, bv, acc[j], 0, 0, 0);
    }
  }
#pragma unroll
  for (int j = 0; j < 6; ++j) {
    int t = 16 * j + l15;
#pragma unroll
    for (int r = 0; r < 4; ++r) {
      int bm = bmw + quad * 4 + r;
      P[((size_t)ks * nbm + bm) * TTX + t] = acc[j][r];
    }
  }
}

__global__ __launch_bounds__(256) void head_reduce(
    const float* __restrict__ P, const float* __restrict__ hb,
    float* __restrict__ out, int nbm, int bm_off) {
  int i = blockIdx.x * 256 + threadIdx.x;    // nbm*96
  int t = i % TTX;
  int bm = i / TTX;
  float s = hb[t];
#pragma unroll
  for (int ks = 0; ks < 8; ++ks) s += P[((size_t)ks * nbm + bm) * TTX + t];
  out[(size_t)(bm_off + bm) * TTX + t] = s;
}

// ---------------------------------------------------------------------------
extern "C" void kernel_launch(void* const* d_in, const int* in_sizes, int n_in,
                              void* d_out, int out_size, void* d_ws, size_t ws_size,
                              hipStream_t stream) {
  const float* x      = (const float*)d_in[0];
  const float* emb_w  = (const float*)d_in[1];
  const float* emb_b  = (const float*)d_in[2];
  const float* head_w = (const float*)d_in[3];
  const float* head_b = (const float*)d_in[4];
  const float* dw_w1  = (const float*)d_in[5];
  const float* dw_b1  = (const float*)d_in[6];
  const float* f11_w  = (const float*)d_in[7];
  const float* f11_b  = (const float*)d_in[8];
  const float* f12_w  = (const float*)d_in[9];
  const float* f12_b  = (const float*)d_in[10];
  const float* dw_w2  = (const float*)d_in[11];
  const float* dw_b2  = (const float*)d_in[12];
  const float* f21_w  = (const float*)d_in[13];
  const float* f21_b  = (const float*)d_in[14];
  const float* f22_w  = (const float*)d_in[15];
  const float* f22_b  = (const float*)d_in[16];

  // fixed: 4 conv wT (98304 bf16 each) + hwT (786432 bf16)
  const size_t WEL = 98304, HWEL = 786432;
  __hip_bfloat16* wt11 = (__hip_bfloat16*)d_ws;
  __hip_bfloat16* wt12 = wt11 + WEL;
  __hip_bfloat16* wt21 = wt12 + WEL;
  __hip_bfloat16* wt22 = wt21 + WEL;
  __hip_bfloat16* hwT  = wt22 + WEL;
  char* dyn = (char*)(hwT + HWEL);
  const size_t fixed_bytes = (4 * WEL + HWEL) * 2;

  const size_t YP_B = (size_t)PROWS * PCOLS * DDX * 2;    // 1,114,880
  const size_t HP_B = (size_t)PROWS * PCOLS * RDX * 2;    // 2,229,760
  const size_t X_B  = (size_t)MMX * NNX * DDX * 4;        // 2,097,152
  const size_t XB_B = (size_t)MMX * NNX * DDX * 2;        // 1,048,576
  const size_t P_B  = (size_t)8 * MMX * TTX * 4;          //   196,608
  const size_t PER_B = YP_B + HP_B + X_B + XB_B + P_B;
  int Bc = 32;
  while (Bc > 1 && fixed_bytes + (size_t)Bc * PER_B > ws_size) Bc >>= 1;

  __hip_bfloat16* Yp = (__hip_bfloat16*)dyn;
  __hip_bfloat16* Hp = (__hip_bfloat16*)(dyn + (size_t)Bc * YP_B);
  float* X  = (float*)(dyn + (size_t)Bc * (YP_B + HP_B));
  __hip_bfloat16* Xb = (__hip_bfloat16*)(dyn + (size_t)Bc * (YP_B + HP_B + X_B));
  float* P  = (float*)(dyn + (size_t)Bc * (YP_B + HP_B + X_B + XB_B));
  const int nbm = Bc * MMX;

  // prep (once per launch)
  castw_kernel<<<384, 256, 0, stream>>>(f11_w, wt11, RDX, DDX);
  castw_kernel<<<384, 256, 0, stream>>>(f12_w, wt12, DDX, RDX);
  castw_kernel<<<384, 256, 0, stream>>>(f21_w, wt21, RDX, DDX);
  castw_kernel<<<384, 256, 0, stream>>>(f22_w, wt22, DDX, RDX);
  headw_kernel<<<3072, 256, 0, stream>>>(head_w, hwT);
  // zero padded halo buffers (ws is re-poisoned before every timed launch)
  hipMemsetAsync(Yp, 0, (size_t)Bc * (YP_B + HP_B), stream);

  for (int b0 = 0; b0 < 32; b0 += Bc) {
    int bm_off = b0 * MMX;
    embed_kernel<<<Bc * 2048, 256, 0, stream>>>(x, emb_w, emb_b, X, bm_off);

    for (int l = 0; l < 2; ++l) {
      const float* dwW = l ? dw_w2 : dw_w1;
      const float* dwB = l ? dw_b2 : dw_b1;
      const __hip_bfloat16* w1 = l ? wt21 : wt11;
      const float* b1 = l ? f21_b : f11_b;
      const __hip_bfloat16* w2 = l ? wt22 : wt12;
      const float* b2 = l ? f22_b : f12_b;

      dw_kernel<<<Bc * 32, 256, 0, stream>>>(X, dwW, dwB, Yp);
      conv_lds<DDX, RDX, true, 1>
          <<<Bc * MMX, 256, 0, stream>>>(Yp, w1, b1, Hp, nullptr, nullptr);
      conv_lds<RDX, DDX, false, 2>
          <<<Bc * MMX, 256, 0, stream>>>(Hp, w2, b2, nullptr, X, Xb);
    }

    head_split<<<Bc * 8, 256, 0, stream>>>(Xb, hwT, P, nbm);
    head_reduce<<<Bc * 24, 256, 0, stream>>>(P, head_b, (float*)d_out, nbm, bm_off);
  }
}